// Round 6
// baseline (1752.247 us; speedup 1.0000x reference)
//
#include <hip/hip_runtime.h>
#include <math.h>

#define B 64
#define TF 64
#define TE 32
#define E_DIM 40
#define H 100
#define H2 200
#define H3 300
#define SP 256
#define EV 20000
#define ROWS (B*TF)        // 4096
#define OC 1312            // OUT cols: xs300 | hs300 | Rsc200 | RY256 | ccrd256

// ---- MALL-coherent (cross-XCD) data access via compiler-lowered scoped atomics ----
// Agent-scope relaxed atomic load/store bypasses the non-coherent per-XCD L2 and
// operates at the MALL -> no acquire/release cache maintenance needed for DATA.
__device__ __forceinline__ float cload(const float* p) {
  return __hip_atomic_load(const_cast<float*>(p), __ATOMIC_RELAXED, __HIP_MEMORY_SCOPE_AGENT);
}
__device__ __forceinline__ float2 cload2(const float* p) {
  unsigned long long u = __hip_atomic_load(
      const_cast<unsigned long long*>((const unsigned long long*)p),
      __ATOMIC_RELAXED, __HIP_MEMORY_SCOPE_AGENT);
  float2 r;
  r.x = __uint_as_float((unsigned)u);
  r.y = __uint_as_float((unsigned)(u >> 32));
  return r;
}
__device__ __forceinline__ void cstore(float* p, float v) {
  __hip_atomic_store(p, v, __ATOMIC_RELAXED, __HIP_MEMORY_SCOPE_AGENT);
}

// ---------------- setup: v = rowmean(sp2_W), c2 = mean(sp2_b) ----------------
__global__ __launch_bounds__(256) void k_setup(const float* sp2_W, const float* sp2_b,
                                               float* v, float* c2) {
  if (blockIdx.x == 0) {
    int k = threadIdx.x;
    float s = 0.f;
    for (int j = 0; j < SP; ++j) s += sp2_W[k*SP + j];
    v[k] = s * (1.f/256.f);
  } else if (threadIdx.x == 0) {
    float s = 0.f;
    for (int j = 0; j < SP; ++j) s += sp2_b[j];
    *c2 = s * (1.f/256.f);
  }
}

// ---------------- encoder xs = embed @ enc_W + enc_b[0] ----------------
__global__ __launch_bounds__(320) void k_embed(const int* enc_in, const float* femb,
        const float* enc_W, const float* enc_b, float* xs_all) {
  int row = blockIdx.x;
  int j = threadIdx.x;
  __shared__ __align__(16) float emb[E_DIM];
  int tok = enc_in[row];
  if (j < E_DIM) emb[j] = femb[tok*E_DIM + j];
  __syncthreads();
  if (j < H3) {
    float acc = enc_b[j];
    #pragma unroll
    for (int k = 0; k < E_DIM; ++k) acc += emb[k]*enc_W[k*H3 + j];
    xs_all[row*H3 + j] = acc;
  }
}

// ---------------- encoder GRU recurrence ----------------
__global__ __launch_bounds__(192) void k_enc(const float* __restrict__ enc_U,
        const float* __restrict__ enc_b, const float* __restrict__ xs_all,
        float* __restrict__ enc_T, float* __restrict__ h_state) {
  int b = blockIdx.x, t = threadIdx.x;
  __shared__ __align__(16) float hsh[104];
  __shared__ __align__(16) float hs[304];

  float2 Ur[100];
  float2 bias = {0.f, 0.f};
  if (t < 150) {
    const float* base = enc_U + 2*t;
    #pragma unroll
    for (int k = 0; k < 100; ++k) Ur[k] = *(const float2*)(base + k*H3);
    bias = *(const float2*)(enc_b + H3 + 2*t);
  }
  if (t < H) hsh[t] = 0.f;
  __syncthreads();

  #pragma unroll 1
  for (int step = 0; step < TF; ++step) {
    int row = b*TF + step;
    float xz = 0.f, xr = 0.f, xh = 0.f;
    if (t < H) {
      xz = xs_all[row*H3 + t];
      xr = xs_all[row*H3 + 100 + t];
      xh = xs_all[row*H3 + 200 + t];
    }
    if (t < 150) {
      float a0 = bias.x, a1 = bias.y;
      const float4* h4 = (const float4*)hsh;
      #pragma unroll
      for (int k4 = 0; k4 < 25; ++k4) {
        float4 hv = h4[k4];
        a0 += hv.x*Ur[k4*4+0].x + hv.y*Ur[k4*4+1].x + hv.z*Ur[k4*4+2].x + hv.w*Ur[k4*4+3].x;
        a1 += hv.x*Ur[k4*4+0].y + hv.y*Ur[k4*4+1].y + hv.z*Ur[k4*4+2].y + hv.w*Ur[k4*4+3].y;
      }
      hs[2*t]   = a0;
      hs[2*t+1] = a1;
    }
    __syncthreads();
    if (t < H) {
      float z = 1.f/(1.f+expf(-(xz + hs[t])));
      float r = 1.f/(1.f+expf(-(xr + hs[100+t])));
      float cand = tanhf(xh + r*hs[200+t]);
      float hn = z*hsh[t] + (1.f-z)*cand;
      hsh[t] = hn;
      enc_T[t*ROWS + row] = hn;
    }
    __syncthreads();
  }
  if (t < H) h_state[b*H + t] = hsh[t];
}

// ---------------- sync ----------------
// signal: RELEASE fetch_add (round-4-proven cross-XCD visible). The wbl2 it emits is
//         near-free now: comm stores already went to MALL, little dirty L2 remains.
// wait:   RELAXED polling; NO acquire fence needed — all cross-block data is read
//         via MALL-coherent scoped-atomic loads (never served from stale L2).
__device__ __forceinline__ void sig(unsigned* p) {
  __hip_atomic_fetch_add(p, 1u, __ATOMIC_RELEASE, __HIP_MEMORY_SCOPE_AGENT);
}
__device__ __forceinline__ void wait16(unsigned* p) {
  while (__hip_atomic_load(p, __ATOMIC_RELAXED, __HIP_MEMORY_SCOPE_AGENT) < 16u) {
    __builtin_amdgcn_s_sleep(1);
  }
}

// ---------------- persistent decoder: 128 blocks, flag-synced pipeline ----------------
__global__ __launch_bounds__(512, 2) void k_coop(
    const float* __restrict__ enc_T, const float* __restrict__ h_st,
    const float* __restrict__ dec_W, const float* __restrict__ dec_U,
    const float* __restrict__ dec_b,
    const float* __restrict__ sp1_W, const float* __restrict__ sp1_b,
    const float* __restrict__ att_W1, const float* __restrict__ att_W2,
    const float* __restrict__ v_g, const float* __restrict__ c2p,
    float* __restrict__ rd_g, float* __restrict__ h_g,
    float* __restrict__ OUT_g, float* __restrict__ dec_o,
    unsigned* __restrict__ cnt) {
  __shared__ float LD[38464];          // 153856 B union
  int tid = threadIdx.x, blk = blockIdx.x;
  int w = tid >> 6, lane = tid & 63;
  unsigned* C1 = cnt;                  // [32][4]  P1 -> P2
  unsigned* C2 = cnt + 128;            // [32][4]  P2 -> P1
  float c2 = *c2p;

  if (blk < 64) {
    // =========================== P1 role ===========================
    int b = blk, bg = b >> 4;
    float* Psc  = LD;                  // [64][200]
    float* PY   = LD + 12800;          // [64][256]
    float* encL = LD + 29184;          // [100][64]
    float* OUTst= LD + 35584;          // [1312]
    float* hL   = LD + 36896;          // [104]
    float* rdL  = LD + 37000;          // [104]
    float* hWs  = LD + 37104;          // [200]
    float* qs   = LD + 37304;          // [200]
    float* ccs  = LD + 37504;          // [256]
    float* vL   = LD + 37760;          // [256]
    float* spb  = LD + 38016;          // [256]
    float* scor = LD + 38272;          // [64]
    float* alph = LD + 38336;          // [64]
    float* gsh  = LD + 38400;          // [64]

    // ---- hoisted weights (once) ----
    int colA = tid >> 1, halfA = tid & 1;    // cc_h: 2 threads per col, k-split
    float4 wA4[13];
    #pragma unroll
    for (int i = 0; i < 13; ++i) {
      int k = halfA*52 + i*4;
      wA4[i].x = sp1_W[(k+0)*SP + colA];
      wA4[i].y = sp1_W[(k+1)*SP + colA];
      wA4[i].z = sp1_W[(k+2)*SP + colA];
      wA4[i].w = sp1_W[(k+3)*SP + colA];
    }
    float4 wB4[25];                          // hW (tid<200) / q (200<=tid<400)
    if (tid < 400) {
      const float* Wm = (tid < 200) ? att_W1 : att_W2;
      int cB = (tid < 200) ? tid : tid - 200;
      #pragma unroll
      for (int i = 0; i < 25; ++i) {
        wB4[i].x = Wm[(i*4+0)*H2 + cB];
        wB4[i].y = Wm[(i*4+1)*H2 + cB];
        wB4[i].z = Wm[(i*4+2)*H2 + cB];
        wB4[i].w = Wm[(i*4+3)*H2 + cB];
      }
    }

    // ---- prologue: stage state ----
    for (int i = tid; i < 6400; i += 512)
      encL[i] = enc_T[(i >> 6)*ROWS + b*64 + (i & 63)];
    if (tid < 104) { hL[tid] = (tid < 100) ? h_st[b*100 + tid] : 0.f; rdL[tid] = 0.f; }
    if (tid < 100) cstore(h_g + b*100 + tid, h_st[b*100 + tid]);
    if (tid < 256) { vL[tid] = v_g[tid]; spb[tid] = sp1_b[tid]; }
    __syncthreads();

    // ---- P-init: Psc/PY = enc @ [attW1 bottom | sp1W enc-part] ----
    {
      int t = tid >> 3, c8 = tid & 7;
      for (int c = c8; c < 456; c += 8) {
        const float* wp; int ld;
        if (c < 200) { wp = att_W1 + 100*H2 + c; ld = H2; }
        else         { wp = sp1_W + 200*SP + (c-200); ld = SP; }
        float a = 0.f;
        #pragma unroll 4
        for (int k = 0; k < 100; ++k) a += encL[k*64 + t] * wp[k*ld];
        if (c < 200) Psc[t*200 + c] = a; else PY[t*256 + (c-200)] = a;
      }
    }
    // hW/q from h(-1)
    if (tid < 400) {
      float a = 0.f;
      const float4* h4 = (const float4*)hL;
      #pragma unroll
      for (int i = 0; i < 25; ++i) {
        float4 hv = h4[i];
        a += hv.x*wB4[i].x + hv.y*wB4[i].y + hv.z*wB4[i].z + hv.w*wB4[i].w;
      }
      if (tid < 200) hWs[tid] = a; else qs[tid-200] = a;
    }
    __syncthreads();

    #pragma unroll 1
    for (int s = 0; s < TE; ++s) {
      if (s > 0) {
        // wait for OUT(s-1)
        if (tid == 0) wait16(&C2[(s-1)*4 + bg]);
        __syncthreads();
        for (int i = tid; i < 656; i += 512) {        // 1312 floats = 656 float2
          float2 vv = cload2(OUT_g + b*OC + i*2);
          *(float2*)(OUTst + i*2) = vv;
        }
        __syncthreads();
        // h-update -> h(s-1)
        if (tid < 100) {
          float xz = OUTst[tid], xr = OUTst[100+tid], xh = OUTst[200+tid];
          float hz = OUTst[300+tid], hr = OUTst[400+tid], hh = OUTst[500+tid];
          float hv = hL[tid];
          float z = 1.f/(1.f+expf(-(xz+hz)));
          float r = 1.f/(1.f+expf(-(xr+hr)));
          float cand = tanhf(xh + r*hh);
          float hn = z*hv + (1.f-z)*cand;
          hL[tid] = hn;
          cstore(h_g + b*100 + tid, hn);
          dec_o[(b*TE + (s-1))*H + tid] = hn;
        }
        __syncthreads();
        // cc_h (k-split pairs) + hW/q from h(s-1)
        {
          float a = 0.f;
          const float4* h4 = (const float4*)(hL + halfA*52);
          #pragma unroll
          for (int i = 0; i < 13; ++i) {
            float4 hv = h4[i];
            a += hv.x*wA4[i].x + hv.y*wA4[i].y + hv.z*wA4[i].z + hv.w*wA4[i].w;
          }
          a += __shfl_xor(a, 1);
          if (halfA == 0) ccs[colA] = a + OUTst[1056 + colA] + spb[colA];
        }
        if (tid < 400) {
          float a = 0.f;
          const float4* h4 = (const float4*)hL;
          #pragma unroll
          for (int i = 0; i < 25; ++i) {
            float4 hv = h4[i];
            a += hv.x*wB4[i].x + hv.y*wB4[i].y + hv.z*wB4[i].z + hv.w*wB4[i].w;
          }
          if (tid < 200) hWs[tid] = a; else qs[tid-200] = a;
        }
        __syncthreads();
        // gate g(s-1) (reads PY pre-blend)
        #pragma unroll
        for (int i = 0; i < 8; ++i) {
          int t = w*8 + i;
          float gp = 0.f;
          #pragma unroll
          for (int jj = 0; jj < 4; ++jj) {
            int j = lane + jj*64;
            gp += fmaxf(ccs[j] + PY[t*256 + j], 0.f) * vL[j];
          }
          #pragma unroll
          for (int mk = 32; mk >= 1; mk >>= 1) gp += __shfl_xor(gp, mk);
          if (lane == 0) gsh[t] = 1.f/(1.f+expf(-(gp + c2)));
        }
        __syncthreads();
        // blend PY + enc, and FUSED Psc-blend + scores(s)
        #pragma unroll
        for (int i = 0; i < 8; ++i) {
          int t = w*8 + i;
          float gt = gsh[t], om = 1.f - gt;
          #pragma unroll
          for (int jj = 0; jj < 4; ++jj) {
            int j = lane + jj*64;
            PY[t*256 + j] = gt*PY[t*256 + j] + om*OUTst[800 + j];
          }
        }
        for (int i = tid; i < 6400; i += 512) {
          int k = i >> 6, t = i & 63;
          float gt = gsh[t];
          encL[i] = gt*encL[i] + (1.f - gt)*rdL[k];
        }
        #pragma unroll
        for (int i = 0; i < 8; ++i) {
          int t = w*8 + i;
          float gt = gsh[t], om = 1.f - gt;
          float sp = 0.f;
          for (int c = lane; c < 200; c += 64) {
            float nv = gt*Psc[t*200 + c] + om*OUTst[600 + c];
            Psc[t*200 + c] = nv;
            sp += tanhf(hWs[c] + nv) * qs[c];
          }
          #pragma unroll
          for (int mk = 32; mk >= 1; mk >>= 1) sp += __shfl_xor(sp, mk);
          if (lane == 0) scor[t] = sp;
        }
        __syncthreads();
      } else {
        // scores(0) on fresh Psc
        #pragma unroll
        for (int i = 0; i < 8; ++i) {
          int t = w*8 + i;
          float sp = 0.f;
          for (int c = lane; c < 200; c += 64)
            sp += tanhf(hWs[c] + Psc[t*200 + c]) * qs[c];
          #pragma unroll
          for (int mk = 32; mk >= 1; mk >>= 1) sp += __shfl_xor(sp, mk);
          if (lane == 0) scor[t] = sp;
        }
        __syncthreads();
      }
      // softmax
      if (w == 0) {
        float sc = scor[lane];
        float m = sc;
        #pragma unroll
        for (int mk = 32; mk >= 1; mk >>= 1) m = fmaxf(m, __shfl_xor(m, mk));
        float ex = expf(sc - m);
        float ssum = ex;
        #pragma unroll
        for (int mk = 32; mk >= 1; mk >>= 1) ssum += __shfl_xor(ssum, mk);
        alph[lane] = ex / ssum;
      }
      __syncthreads();
      // rd(s)
      float al = alph[lane];
      #pragma unroll
      for (int i = 0; i < 13; ++i) {
        int j = w + i*8;
        if (j < 100) {
          float vs = al * encL[j*64 + lane];
          #pragma unroll
          for (int mk = 32; mk >= 1; mk >>= 1) vs += __shfl_xor(vs, mk);
          if (lane == 0) { rdL[j] = vs; cstore(rd_g + b*100 + j, vs); }
        }
      }
      __syncthreads();
      if (tid == 0) sig(&C1[s*4 + bg]);
    }
    // epilogue: h(31) -> dec_o
    if (tid == 0) wait16(&C2[31*4 + bg]);
    __syncthreads();
    for (int i = tid; i < 300; i += 512) {            // first 600 floats
      float2 vv = cload2(OUT_g + b*OC + i*2);
      *(float2*)(OUTst + i*2) = vv;
    }
    __syncthreads();
    if (tid < 100) {
      float xz = OUTst[tid], xr = OUTst[100+tid], xh = OUTst[200+tid];
      float hz = OUTst[300+tid], hr = OUTst[400+tid], hh = OUTst[500+tid];
      float hv = hL[tid];
      float z = 1.f/(1.f+expf(-(xz+hz)));
      float r = 1.f/(1.f+expf(-(xr+hr)));
      float cand = tanhf(xh + r*hh);
      dec_o[(b*TE + 31)*H + tid] = z*hv + (1.f-z)*cand;
    }
  } else {
    // =========================== P2 role ===========================
    int pb = blk - 64;                 // 0..63
    int bg = pb >> 4, cg = pb & 15;
    int c0 = cg*82;
    float* Wt   = LD;                  // [100][84]
    float* rd16 = LD + 8400;           // [16][112]
    float* h16  = LD + 10192;          // [16][112]
    float* bias = LD + 11984;          // [84]

    for (int i = tid; i < 8200; i += 512) {
      int k = i / 82, cc = i - k*82;
      int c = c0 + cc;
      float wv;
      if (c < 300)       wv = dec_W[k*H3 + c];
      else if (c < 600)  wv = dec_U[k*H3 + (c-300)];
      else if (c < 800)  wv = att_W1[(100+k)*H2 + (c-600)];
      else if (c < 1056) wv = sp1_W[(200+k)*SP + (c-800)];
      else               wv = sp1_W[(100+k)*SP + (c-1056)];
      Wt[k*84 + cc] = wv;
    }
    for (int i = tid; i < 84; i += 512) {
      int c = c0 + i;
      bias[i] = (i < 82 && c < 600) ? dec_b[c] : 0.f;
    }

    #pragma unroll 1
    for (int s = 0; s < TE; ++s) {
      if (tid == 0) wait16(&C1[s*4 + bg]);
      __syncthreads();
      for (int i = tid; i < 800; i += 512) {   // 16 batches x 50 float2 each
        int bb = i / 50, k2 = i - bb*50;
        float2 rv = cload2(rd_g + (bg*16 + bb)*100 + k2*2);
        float2 hv = cload2(h_g  + (bg*16 + bb)*100 + k2*2);
        *(float2*)(rd16 + bb*112 + k2*2) = rv;
        *(float2*)(h16  + bb*112 + k2*2) = hv;
      }
      __syncthreads();
      #pragma unroll
      for (int r = 0; r < 3; ++r) {
        int o = r*512 + tid;
        if (o < 1312) {
          int cc = o >> 4, bb = o & 15;
          int c = c0 + cc;
          const float* in = (c >= 300 && c < 600) ? (h16 + bb*112) : (rd16 + bb*112);
          float a = bias[cc];
          const float4* in4 = (const float4*)in;
          #pragma unroll
          for (int k4 = 0; k4 < 25; ++k4) {
            float4 iv = in4[k4];
            a += iv.x*Wt[(k4*4+0)*84 + cc] + iv.y*Wt[(k4*4+1)*84 + cc]
               + iv.z*Wt[(k4*4+2)*84 + cc] + iv.w*Wt[(k4*4+3)*84 + cc];
          }
          cstore(OUT_g + (bg*16 + bb)*OC + c, a);
        }
      }
      __syncthreads();
      if (tid == 0) sig(&C2[s*4 + bg]);
    }
  }
}

// ---------------- ff1: hid = relu(dec_out @ ff1_W + b) ----------------
__global__ __launch_bounds__(128) void k_ff1(const float* dec_out, const float* ff1_W,
        const float* ff1_b, float* hid) {
  int row = blockIdx.x, j = threadIdx.x;
  __shared__ __align__(16) float a[104];
  if (j < H) a[j] = dec_out[row*H + j];
  __syncthreads();
  if (j < H) {
    float acc = ff1_b[j];
    const float4* a4 = (const float4*)a;
    #pragma unroll
    for (int k4 = 0; k4 < 25; ++k4) {
      float4 av = a4[k4];
      int k = k4*4;
      acc += av.x*ff1_W[(k+0)*H+j] + av.y*ff1_W[(k+1)*H+j] + av.z*ff1_W[(k+2)*H+j] + av.w*ff1_W[(k+3)*H+j];
    }
    hid[row*H + j] = fmaxf(acc, 0.f);
  }
}

// ---------------- logits GEMM: [2048,100] x [100,20000] ----------------
#define KC 20
__global__ __launch_bounds__(256) void k_logits(const float* hid, const float* ff2_W,
        const float* ff2_b, float* out) {
  int bx = blockIdx.x, by = blockIdx.y;
  int tid = threadIdx.x;
  int tx = tid & 15, ty = tid >> 4;
  __shared__ __align__(16) float At[KC*132];
  __shared__ __align__(16) float Wt[KC*132];
  int r0 = by*128;
  int c0 = bx*128;
  float acc[8][8];
  #pragma unroll
  for (int i = 0; i < 8; ++i) {
    #pragma unroll
    for (int j = 0; j < 8; ++j) acc[i][j] = 0.f;
  }
  for (int kc = 0; kc < 100; kc += KC) {
    __syncthreads();
    for (int i = tid; i < 128*KC; i += 256) {
      int r = i & 127, kk = i >> 7;
      At[kk*132 + r] = hid[(r0+r)*H + kc + kk];
    }
    for (int i = tid; i < 128*KC; i += 256) {
      int cidx = i & 127, kk = i >> 7;
      int gc = c0 + cidx;
      Wt[kk*132 + cidx] = (gc < EV) ? ff2_W[(size_t)(kc+kk)*EV + gc] : 0.f;
    }
    __syncthreads();
    #pragma unroll
    for (int kk = 0; kk < KC; ++kk) {
      const float* Ar = At + kk*132;
      const float* Wr = Wt + kk*132;
      float4 a0 = *(const float4*)(Ar + ty*4);
      float4 a1 = *(const float4*)(Ar + 64 + ty*4);
      float4 w0 = *(const float4*)(Wr + tx*4);
      float4 w1 = *(const float4*)(Wr + 64 + tx*4);
      float av[8] = {a0.x,a0.y,a0.z,a0.w,a1.x,a1.y,a1.z,a1.w};
      float wv[8] = {w0.x,w0.y,w0.z,w0.w,w1.x,w1.y,w1.z,w1.w};
      #pragma unroll
      for (int i = 0; i < 8; ++i) {
        #pragma unroll
        for (int j = 0; j < 8; ++j) acc[i][j] += av[i]*wv[j];
      }
    }
  }
  #pragma unroll
  for (int i = 0; i < 8; ++i) {
    int r = r0 + ty*4 + (i < 4 ? i : 60 + i);
    float* orow = out + (size_t)r*EV;
    int ca = c0 + tx*4;
    if (ca < EV) {
      float4 bb = *(const float4*)(ff2_b + ca);
      float4 val = {acc[i][0]+bb.x, acc[i][1]+bb.y, acc[i][2]+bb.z, acc[i][3]+bb.w};
      *(float4*)(orow + ca) = val;
    }
    int cb = c0 + 64 + tx*4;
    if (cb < EV) {
      float4 bb = *(const float4*)(ff2_b + cb);
      float4 val = {acc[i][4]+bb.x, acc[i][5]+bb.y, acc[i][6]+bb.z, acc[i][7]+bb.w};
      *(float4*)(orow + cb) = val;
    }
  }
}

// ---------------- in-place row softmax ----------------
__global__ __launch_bounds__(256) void k_softmax(float* out) {
  int row = blockIdx.x, tid = threadIdx.x;
  float* p = out + (size_t)row*EV;
  float m = -1e30f, ssum = 0.f;
  for (int j = tid; j < EV; j += 256) {
    float x = p[j];
    if (x > m) { ssum = ssum*expf(m - x) + 1.f; m = x; }
    else ssum += expf(x - m);
  }
  __shared__ float sm[256], ss[256];
  sm[tid] = m; ss[tid] = ssum;
  __syncthreads();
  for (int st = 128; st >= 1; st >>= 1) {
    if (tid < st) {
      float m2 = sm[tid+st], s2 = ss[tid+st];
      float M = fmaxf(sm[tid], m2);
      ss[tid] = ss[tid]*expf(sm[tid]-M) + s2*expf(m2-M);
      sm[tid] = M;
    }
    __syncthreads();
  }
  float M = sm[0];
  float inv = 1.f/ss[0];
  for (int j = tid; j < EV; j += 256) {
    p[j] = expf(p[j] - M) * inv;
  }
}

extern "C" void kernel_launch(void* const* d_in, const int* in_sizes, int n_in,
                              void* d_out, int out_size, void* d_ws, size_t ws_size,
                              hipStream_t stream) {
  (void)in_sizes; (void)n_in; (void)out_size;
  const int*   enc_in  = (const int*)d_in[0];
  const float* femb    = (const float*)d_in[2];
  const float* enc_W   = (const float*)d_in[4];
  const float* enc_U   = (const float*)d_in[5];
  const float* enc_b   = (const float*)d_in[6];
  const float* dec_W   = (const float*)d_in[7];
  const float* dec_U   = (const float*)d_in[8];
  const float* dec_b   = (const float*)d_in[9];
  const float* att_W1  = (const float*)d_in[10];
  const float* att_W2  = (const float*)d_in[11];
  const float* sp1_W   = (const float*)d_in[12];
  const float* sp1_b   = (const float*)d_in[13];
  const float* sp2_W   = (const float*)d_in[14];
  const float* sp2_b   = (const float*)d_in[15];
  const float* ff1_W   = (const float*)d_in[16];
  const float* ff1_b   = (const float*)d_in[17];
  const float* ff2_W   = (const float*)d_in[18];
  const float* ff2_b   = (const float*)d_in[19];
  float* out = (float*)d_out;
  float* ws  = (float*)d_ws;

  float* enc_T  = ws + 0;          // 409600
  float* h_st   = ws + 409600;     // 6400
  float* rd_g   = ws + 416000;     // 6400
  float* h_g    = ws + 422400;     // 6400
  float* OUT_g  = ws + 428800;     // 64*1312 = 83968
  float* dec_o  = ws + 512768;     // 204800
  float* hid    = ws + 717568;     // 204800
  float* vbuf   = ws + 922368;     // 256
  float* c2buf  = ws + 922624;     // 32 (pad)
  unsigned* cnt = (unsigned*)(ws + 922656);  // 256 uints
  float* xs_all = ws + 922912;     // 1228800 (dead after k_enc)
  if (ws_size < (size_t)2151712*4) return;   // ~8.6 MB

  k_setup<<<2, 256, 0, stream>>>(sp2_W, sp2_b, vbuf, c2buf);
  k_embed<<<4096, 320, 0, stream>>>(enc_in, femb, enc_W, enc_b, xs_all);
  k_enc<<<64, 192, 0, stream>>>(enc_U, enc_b, xs_all, enc_T, h_st);
  hipMemsetAsync(cnt, 0, 256*sizeof(unsigned), stream);
  k_coop<<<128, 512, 0, stream>>>(enc_T, h_st, dec_W, dec_U, dec_b, sp1_W, sp1_b,
                                  att_W1, att_W2, vbuf, c2buf,
                                  rd_g, h_g, OUT_g, dec_o, cnt);
  k_ff1<<<2048, 128, 0, stream>>>(dec_o, ff1_W, ff1_b, hid);
  k_logits<<<dim3(157, 16), 256, 0, stream>>>(hid, ff2_W, ff2_b, out);
  k_softmax<<<2048, 256, 0, stream>>>(out);
}

// Round 7
// 1620.474 us; speedup vs baseline: 1.0813x; 1.0813x over previous
//
#include <hip/hip_runtime.h>
#include <math.h>

#define B 64
#define TF 64
#define TE 32
#define E_DIM 40
#define H 100
#define H2 200
#define H3 300
#define SP 256
#define EV 20000
#define ROWS (B*TF)        // 4096
#define OC 1312            // OUT cols: xs300 | hs300 | Rsc200 | RY256 | ccrd256

// ---- MALL-coherent (cross-XCD) data access via compiler-lowered scoped atomics ----
// Agent-scope atomic load/store bypasses the non-coherent per-XCD L2 and operates at
// the MALL -> no acquire/release cache maintenance needed for DATA.
__device__ __forceinline__ float cload(const float* p) {
  return __hip_atomic_load(const_cast<float*>(p), __ATOMIC_RELAXED, __HIP_MEMORY_SCOPE_AGENT);
}
__device__ __forceinline__ float2 cload2(const float* p) {
  unsigned long long u = __hip_atomic_load(
      const_cast<unsigned long long*>((const unsigned long long*)p),
      __ATOMIC_RELAXED, __HIP_MEMORY_SCOPE_AGENT);
  float2 r;
  r.x = __uint_as_float((unsigned)u);
  r.y = __uint_as_float((unsigned)(u >> 32));
  return r;
}
__device__ __forceinline__ void cstore(float* p, float v) {
  __hip_atomic_store(p, v, __ATOMIC_RELAXED, __HIP_MEMORY_SCOPE_AGENT);
}

// ---------------- setup: v = rowmean(sp2_W), c2 = mean(sp2_b) ----------------
__global__ __launch_bounds__(256) void k_setup(const float* sp2_W, const float* sp2_b,
                                               float* v, float* c2) {
  if (blockIdx.x == 0) {
    int k = threadIdx.x;
    float s = 0.f;
    for (int j = 0; j < SP; ++j) s += sp2_W[k*SP + j];
    v[k] = s * (1.f/256.f);
  } else if (threadIdx.x == 0) {
    float s = 0.f;
    for (int j = 0; j < SP; ++j) s += sp2_b[j];
    *c2 = s * (1.f/256.f);
  }
}

// ---------------- encoder xs = embed @ enc_W + enc_b[0] ----------------
__global__ __launch_bounds__(320) void k_embed(const int* enc_in, const float* femb,
        const float* enc_W, const float* enc_b, float* xs_all) {
  int row = blockIdx.x;
  int j = threadIdx.x;
  __shared__ __align__(16) float emb[E_DIM];
  int tok = enc_in[row];
  if (j < E_DIM) emb[j] = femb[tok*E_DIM + j];
  __syncthreads();
  if (j < H3) {
    float acc = enc_b[j];
    #pragma unroll
    for (int k = 0; k < E_DIM; ++k) acc += emb[k]*enc_W[k*H3 + j];
    xs_all[row*H3 + j] = acc;
  }
}

// ---------------- encoder GRU recurrence ----------------
__global__ __launch_bounds__(192) void k_enc(const float* __restrict__ enc_U,
        const float* __restrict__ enc_b, const float* __restrict__ xs_all,
        float* __restrict__ enc_T, float* __restrict__ h_state) {
  int b = blockIdx.x, t = threadIdx.x;
  __shared__ __align__(16) float hsh[104];
  __shared__ __align__(16) float hs[304];

  float2 Ur[100];
  float2 bias = {0.f, 0.f};
  if (t < 150) {
    const float* base = enc_U + 2*t;
    #pragma unroll
    for (int k = 0; k < 100; ++k) Ur[k] = *(const float2*)(base + k*H3);
    bias = *(const float2*)(enc_b + H3 + 2*t);
  }
  if (t < H) hsh[t] = 0.f;
  __syncthreads();

  #pragma unroll 1
  for (int step = 0; step < TF; ++step) {
    int row = b*TF + step;
    float xz = 0.f, xr = 0.f, xh = 0.f;
    if (t < H) {
      xz = xs_all[row*H3 + t];
      xr = xs_all[row*H3 + 100 + t];
      xh = xs_all[row*H3 + 200 + t];
    }
    if (t < 150) {
      float a0 = bias.x, a1 = bias.y;
      const float4* h4 = (const float4*)hsh;
      #pragma unroll
      for (int k4 = 0; k4 < 25; ++k4) {
        float4 hv = h4[k4];
        a0 += hv.x*Ur[k4*4+0].x + hv.y*Ur[k4*4+1].x + hv.z*Ur[k4*4+2].x + hv.w*Ur[k4*4+3].x;
        a1 += hv.x*Ur[k4*4+0].y + hv.y*Ur[k4*4+1].y + hv.z*Ur[k4*4+2].y + hv.w*Ur[k4*4+3].y;
      }
      hs[2*t]   = a0;
      hs[2*t+1] = a1;
    }
    __syncthreads();
    if (t < H) {
      float z = 1.f/(1.f+expf(-(xz + hs[t])));
      float r = 1.f/(1.f+expf(-(xr + hs[100+t])));
      float cand = tanhf(xh + r*hs[200+t]);
      float hn = z*hsh[t] + (1.f-z)*cand;
      hsh[t] = hn;
      enc_T[t*ROWS + row] = hn;
    }
    __syncthreads();
  }
  if (t < H) h_state[b*H + t] = hsh[t];
}

// ---------------- sync ----------------
// All cross-block DATA goes through MALL-coherent sc1 accesses and is vmcnt-drained
// by __syncthreads before the signal -> nothing dirty in L2 -> RELAXED signal is
// sufficient (no wbl2 walk, no inv). Agent scope still executes the RMW at the MALL
// (same mechanism as the relaxed polls proven visible in rounds 4/6).
// Each counter padded to its own 128B line: 16 adders/counter contend only with
// themselves, not with other groups/steps.
#define CIDX(s, bg) (((s)*4 + (bg)) << 5)
__device__ __forceinline__ void sig(unsigned* p) {
  __hip_atomic_fetch_add(p, 1u, __ATOMIC_RELAXED, __HIP_MEMORY_SCOPE_AGENT);
}
__device__ __forceinline__ void wait16(unsigned* p) {
  while (__hip_atomic_load(p, __ATOMIC_RELAXED, __HIP_MEMORY_SCOPE_AGENT) < 16u) {
    __builtin_amdgcn_s_sleep(1);
  }
}

// ---------------- persistent decoder: 128 blocks, flag-synced pipeline ----------------
__global__ __launch_bounds__(512, 2) void k_coop(
    const float* __restrict__ enc_T, const float* __restrict__ h_st,
    const float* __restrict__ dec_W, const float* __restrict__ dec_U,
    const float* __restrict__ dec_b,
    const float* __restrict__ sp1_W, const float* __restrict__ sp1_b,
    const float* __restrict__ att_W1, const float* __restrict__ att_W2,
    const float* __restrict__ v_g, const float* __restrict__ c2p,
    float* __restrict__ rd_g, float* __restrict__ h_g,
    float* __restrict__ OUT_g, float* __restrict__ dec_o,
    unsigned* __restrict__ cnt) {
  __shared__ float LD[38464];          // 153856 B union
  int tid = threadIdx.x, blk = blockIdx.x;
  int w = tid >> 6, lane = tid & 63;
  unsigned* C1 = cnt;                  // [32][4] x 32-uint pad  P1 -> P2
  unsigned* C2 = cnt + 4096;           // [32][4] x 32-uint pad  P2 -> P1
  float c2 = *c2p;

  if (blk < 64) {
    // =========================== P1 role ===========================
    int b = blk, bg = b >> 4;
    float* Psc  = LD;                  // [64][200]
    float* PY   = LD + 12800;          // [64][256]
    float* encL = LD + 29184;          // [100][64]
    float* OUTst= LD + 35584;          // [1312]
    float* hL   = LD + 36896;          // [104]
    float* rdL  = LD + 37000;          // [104]
    float* hWs  = LD + 37104;          // [200]
    float* qs   = LD + 37304;          // [200]
    float* ccs  = LD + 37504;          // [256]
    float* vL   = LD + 37760;          // [256]
    float* spb  = LD + 38016;          // [256]
    float* scor = LD + 38272;          // [64]
    float* alph = LD + 38336;          // [64]
    float* gsh  = LD + 38400;          // [64]

    // ---- hoisted weights (once) ----
    int colA = tid >> 1, halfA = tid & 1;    // cc_h: 2 threads per col, k-split
    float4 wA4[13];
    #pragma unroll
    for (int i = 0; i < 13; ++i) {
      int k = halfA*52 + i*4;
      wA4[i].x = sp1_W[(k+0)*SP + colA];
      wA4[i].y = sp1_W[(k+1)*SP + colA];
      wA4[i].z = sp1_W[(k+2)*SP + colA];
      wA4[i].w = sp1_W[(k+3)*SP + colA];
    }
    float4 wB4[25];                          // hW (tid<200) / q (200<=tid<400)
    if (tid < 400) {
      const float* Wm = (tid < 200) ? att_W1 : att_W2;
      int cB = (tid < 200) ? tid : tid - 200;
      #pragma unroll
      for (int i = 0; i < 25; ++i) {
        wB4[i].x = Wm[(i*4+0)*H2 + cB];
        wB4[i].y = Wm[(i*4+1)*H2 + cB];
        wB4[i].z = Wm[(i*4+2)*H2 + cB];
        wB4[i].w = Wm[(i*4+3)*H2 + cB];
      }
    }

    // ---- prologue: stage state ----
    for (int i = tid; i < 6400; i += 512)
      encL[i] = enc_T[(i >> 6)*ROWS + b*64 + (i & 63)];
    if (tid < 104) { hL[tid] = (tid < 100) ? h_st[b*100 + tid] : 0.f; rdL[tid] = 0.f; }
    if (tid < 100) cstore(h_g + b*100 + tid, h_st[b*100 + tid]);
    if (tid < 256) { vL[tid] = v_g[tid]; spb[tid] = sp1_b[tid]; }
    __syncthreads();

    // ---- P-init: Psc/PY = enc @ [attW1 bottom | sp1W enc-part] ----
    {
      int t = tid >> 3, c8 = tid & 7;
      for (int c = c8; c < 456; c += 8) {
        const float* wp; int ld;
        if (c < 200) { wp = att_W1 + 100*H2 + c; ld = H2; }
        else         { wp = sp1_W + 200*SP + (c-200); ld = SP; }
        float a = 0.f;
        #pragma unroll 4
        for (int k = 0; k < 100; ++k) a += encL[k*64 + t] * wp[k*ld];
        if (c < 200) Psc[t*200 + c] = a; else PY[t*256 + (c-200)] = a;
      }
    }
    // hW/q from h(-1)
    if (tid < 400) {
      float a = 0.f;
      const float4* h4 = (const float4*)hL;
      #pragma unroll
      for (int i = 0; i < 25; ++i) {
        float4 hv = h4[i];
        a += hv.x*wB4[i].x + hv.y*wB4[i].y + hv.z*wB4[i].z + hv.w*wB4[i].w;
      }
      if (tid < 200) hWs[tid] = a; else qs[tid-200] = a;
    }
    __syncthreads();

    #pragma unroll 1
    for (int s = 0; s < TE; ++s) {
      if (s > 0) {
        // wait for OUT(s-1)
        if (tid == 0) wait16(&C2[CIDX(s-1, bg)]);
        __syncthreads();
        for (int i = tid; i < 656; i += 512) {        // 1312 floats = 656 float2
          float2 vv = cload2(OUT_g + b*OC + i*2);
          *(float2*)(OUTst + i*2) = vv;
        }
        __syncthreads();
        // h-update -> h(s-1)
        if (tid < 100) {
          float xz = OUTst[tid], xr = OUTst[100+tid], xh = OUTst[200+tid];
          float hz = OUTst[300+tid], hr = OUTst[400+tid], hh = OUTst[500+tid];
          float hv = hL[tid];
          float z = 1.f/(1.f+expf(-(xz+hz)));
          float r = 1.f/(1.f+expf(-(xr+hr)));
          float cand = tanhf(xh + r*hh);
          float hn = z*hv + (1.f-z)*cand;
          hL[tid] = hn;
          cstore(h_g + b*100 + tid, hn);
          dec_o[(b*TE + (s-1))*H + tid] = hn;
        }
        __syncthreads();
        // cc_h (k-split pairs) + hW/q from h(s-1)
        {
          float a = 0.f;
          const float4* h4 = (const float4*)(hL + halfA*52);
          #pragma unroll
          for (int i = 0; i < 13; ++i) {
            float4 hv = h4[i];
            a += hv.x*wA4[i].x + hv.y*wA4[i].y + hv.z*wA4[i].z + hv.w*wA4[i].w;
          }
          a += __shfl_xor(a, 1);
          if (halfA == 0) ccs[colA] = a + OUTst[1056 + colA] + spb[colA];
        }
        if (tid < 400) {
          float a = 0.f;
          const float4* h4 = (const float4*)hL;
          #pragma unroll
          for (int i = 0; i < 25; ++i) {
            float4 hv = h4[i];
            a += hv.x*wB4[i].x + hv.y*wB4[i].y + hv.z*wB4[i].z + hv.w*wB4[i].w;
          }
          if (tid < 200) hWs[tid] = a; else qs[tid-200] = a;
        }
        __syncthreads();
        // gate g(s-1) (reads PY pre-blend)
        #pragma unroll
        for (int i = 0; i < 8; ++i) {
          int t = w*8 + i;
          float gp = 0.f;
          #pragma unroll
          for (int jj = 0; jj < 4; ++jj) {
            int j = lane + jj*64;
            gp += fmaxf(ccs[j] + PY[t*256 + j], 0.f) * vL[j];
          }
          #pragma unroll
          for (int mk = 32; mk >= 1; mk >>= 1) gp += __shfl_xor(gp, mk);
          if (lane == 0) gsh[t] = 1.f/(1.f+expf(-(gp + c2)));
        }
        __syncthreads();
        // blend PY + enc, and FUSED Psc-blend + scores(s)
        #pragma unroll
        for (int i = 0; i < 8; ++i) {
          int t = w*8 + i;
          float gt = gsh[t], om = 1.f - gt;
          #pragma unroll
          for (int jj = 0; jj < 4; ++jj) {
            int j = lane + jj*64;
            PY[t*256 + j] = gt*PY[t*256 + j] + om*OUTst[800 + j];
          }
        }
        for (int i = tid; i < 6400; i += 512) {
          int k = i >> 6, t = i & 63;
          float gt = gsh[t];
          encL[i] = gt*encL[i] + (1.f - gt)*rdL[k];
        }
        #pragma unroll
        for (int i = 0; i < 8; ++i) {
          int t = w*8 + i;
          float gt = gsh[t], om = 1.f - gt;
          float sp = 0.f;
          for (int c = lane; c < 200; c += 64) {
            float nv = gt*Psc[t*200 + c] + om*OUTst[600 + c];
            Psc[t*200 + c] = nv;
            sp += tanhf(hWs[c] + nv) * qs[c];
          }
          #pragma unroll
          for (int mk = 32; mk >= 1; mk >>= 1) sp += __shfl_xor(sp, mk);
          if (lane == 0) scor[t] = sp;
        }
        __syncthreads();
      } else {
        // scores(0) on fresh Psc
        #pragma unroll
        for (int i = 0; i < 8; ++i) {
          int t = w*8 + i;
          float sp = 0.f;
          for (int c = lane; c < 200; c += 64)
            sp += tanhf(hWs[c] + Psc[t*200 + c]) * qs[c];
          #pragma unroll
          for (int mk = 32; mk >= 1; mk >>= 1) sp += __shfl_xor(sp, mk);
          if (lane == 0) scor[t] = sp;
        }
        __syncthreads();
      }
      // softmax
      if (w == 0) {
        float sc = scor[lane];
        float m = sc;
        #pragma unroll
        for (int mk = 32; mk >= 1; mk >>= 1) m = fmaxf(m, __shfl_xor(m, mk));
        float ex = expf(sc - m);
        float ssum = ex;
        #pragma unroll
        for (int mk = 32; mk >= 1; mk >>= 1) ssum += __shfl_xor(ssum, mk);
        alph[lane] = ex / ssum;
      }
      __syncthreads();
      // rd(s)
      float al = alph[lane];
      #pragma unroll
      for (int i = 0; i < 13; ++i) {
        int j = w + i*8;
        if (j < 100) {
          float vs = al * encL[j*64 + lane];
          #pragma unroll
          for (int mk = 32; mk >= 1; mk >>= 1) vs += __shfl_xor(vs, mk);
          if (lane == 0) { rdL[j] = vs; cstore(rd_g + b*100 + j, vs); }
        }
      }
      __syncthreads();
      if (tid == 0) sig(&C1[CIDX(s, bg)]);
    }
    // epilogue: h(31) -> dec_o
    if (tid == 0) wait16(&C2[CIDX(31, bg)]);
    __syncthreads();
    for (int i = tid; i < 300; i += 512) {            // first 600 floats
      float2 vv = cload2(OUT_g + b*OC + i*2);
      *(float2*)(OUTst + i*2) = vv;
    }
    __syncthreads();
    if (tid < 100) {
      float xz = OUTst[tid], xr = OUTst[100+tid], xh = OUTst[200+tid];
      float hz = OUTst[300+tid], hr = OUTst[400+tid], hh = OUTst[500+tid];
      float hv = hL[tid];
      float z = 1.f/(1.f+expf(-(xz+hz)));
      float r = 1.f/(1.f+expf(-(xr+hr)));
      float cand = tanhf(xh + r*hh);
      dec_o[(b*TE + 31)*H + tid] = z*hv + (1.f-z)*cand;
    }
  } else {
    // =========================== P2 role ===========================
    int pb = blk - 64;                 // 0..63
    int bg = pb >> 4, cg = pb & 15;
    int c0 = cg*82;
    float* Wt   = LD;                  // [100][84]
    float* rd16 = LD + 8400;           // [16][112]
    float* h16  = LD + 10192;          // [16][112]
    float* bias = LD + 11984;          // [84]

    for (int i = tid; i < 8200; i += 512) {
      int k = i / 82, cc = i - k*82;
      int c = c0 + cc;
      float wv;
      if (c < 300)       wv = dec_W[k*H3 + c];
      else if (c < 600)  wv = dec_U[k*H3 + (c-300)];
      else if (c < 800)  wv = att_W1[(100+k)*H2 + (c-600)];
      else if (c < 1056) wv = sp1_W[(200+k)*SP + (c-800)];
      else               wv = sp1_W[(100+k)*SP + (c-1056)];
      Wt[k*84 + cc] = wv;
    }
    for (int i = tid; i < 84; i += 512) {
      int c = c0 + i;
      bias[i] = (i < 82 && c < 600) ? dec_b[c] : 0.f;
    }

    #pragma unroll 1
    for (int s = 0; s < TE; ++s) {
      if (tid == 0) wait16(&C1[CIDX(s, bg)]);
      __syncthreads();
      for (int i = tid; i < 800; i += 512) {   // 16 batches x 50 float2 each
        int bb = i / 50, k2 = i - bb*50;
        float2 rv = cload2(rd_g + (bg*16 + bb)*100 + k2*2);
        float2 hv = cload2(h_g  + (bg*16 + bb)*100 + k2*2);
        *(float2*)(rd16 + bb*112 + k2*2) = rv;
        *(float2*)(h16  + bb*112 + k2*2) = hv;
      }
      __syncthreads();
      #pragma unroll
      for (int r = 0; r < 3; ++r) {
        int o = r*512 + tid;
        if (o < 1312) {
          int cc = o >> 4, bb = o & 15;
          int c = c0 + cc;
          const float* in = (c >= 300 && c < 600) ? (h16 + bb*112) : (rd16 + bb*112);
          float a = bias[cc];
          const float4* in4 = (const float4*)in;
          #pragma unroll
          for (int k4 = 0; k4 < 25; ++k4) {
            float4 iv = in4[k4];
            a += iv.x*Wt[(k4*4+0)*84 + cc] + iv.y*Wt[(k4*4+1)*84 + cc]
               + iv.z*Wt[(k4*4+2)*84 + cc] + iv.w*Wt[(k4*4+3)*84 + cc];
          }
          cstore(OUT_g + (bg*16 + bb)*OC + c, a);
        }
      }
      __syncthreads();
      if (tid == 0) sig(&C2[CIDX(s, bg)]);
    }
  }
}

// ---------------- ff1: hid = relu(dec_out @ ff1_W + b) ----------------
__global__ __launch_bounds__(128) void k_ff1(const float* dec_out, const float* ff1_W,
        const float* ff1_b, float* hid) {
  int row = blockIdx.x, j = threadIdx.x;
  __shared__ __align__(16) float a[104];
  if (j < H) a[j] = dec_out[row*H + j];
  __syncthreads();
  if (j < H) {
    float acc = ff1_b[j];
    const float4* a4 = (const float4*)a;
    #pragma unroll
    for (int k4 = 0; k4 < 25; ++k4) {
      float4 av = a4[k4];
      int k = k4*4;
      acc += av.x*ff1_W[(k+0)*H+j] + av.y*ff1_W[(k+1)*H+j] + av.z*ff1_W[(k+2)*H+j] + av.w*ff1_W[(k+3)*H+j];
    }
    hid[row*H + j] = fmaxf(acc, 0.f);
  }
}

// ---------------- logits GEMM: [2048,100] x [100,20000] ----------------
#define KC 20
__global__ __launch_bounds__(256) void k_logits(const float* hid, const float* ff2_W,
        const float* ff2_b, float* out) {
  int bx = blockIdx.x, by = blockIdx.y;
  int tid = threadIdx.x;
  int tx = tid & 15, ty = tid >> 4;
  __shared__ __align__(16) float At[KC*132];
  __shared__ __align__(16) float Wt[KC*132];
  int r0 = by*128;
  int c0 = bx*128;
  float acc[8][8];
  #pragma unroll
  for (int i = 0; i < 8; ++i) {
    #pragma unroll
    for (int j = 0; j < 8; ++j) acc[i][j] = 0.f;
  }
  for (int kc = 0; kc < 100; kc += KC) {
    __syncthreads();
    for (int i = tid; i < 128*KC; i += 256) {
      int r = i & 127, kk = i >> 7;
      At[kk*132 + r] = hid[(r0+r)*H + kc + kk];
    }
    for (int i = tid; i < 128*KC; i += 256) {
      int cidx = i & 127, kk = i >> 7;
      int gc = c0 + cidx;
      Wt[kk*132 + cidx] = (gc < EV) ? ff2_W[(size_t)(kc+kk)*EV + gc] : 0.f;
    }
    __syncthreads();
    #pragma unroll
    for (int kk = 0; kk < KC; ++kk) {
      const float* Ar = At + kk*132;
      const float* Wr = Wt + kk*132;
      float4 a0 = *(const float4*)(Ar + ty*4);
      float4 a1 = *(const float4*)(Ar + 64 + ty*4);
      float4 w0 = *(const float4*)(Wr + tx*4);
      float4 w1 = *(const float4*)(Wr + 64 + tx*4);
      float av[8] = {a0.x,a0.y,a0.z,a0.w,a1.x,a1.y,a1.z,a1.w};
      float wv[8] = {w0.x,w0.y,w0.z,w0.w,w1.x,w1.y,w1.z,w1.w};
      #pragma unroll
      for (int i = 0; i < 8; ++i) {
        #pragma unroll
        for (int j = 0; j < 8; ++j) acc[i][j] += av[i]*wv[j];
      }
    }
  }
  #pragma unroll
  for (int i = 0; i < 8; ++i) {
    int r = r0 + ty*4 + (i < 4 ? i : 60 + i);
    float* orow = out + (size_t)r*EV;
    int ca = c0 + tx*4;
    if (ca < EV) {
      float4 bb = *(const float4*)(ff2_b + ca);
      float4 val = {acc[i][0]+bb.x, acc[i][1]+bb.y, acc[i][2]+bb.z, acc[i][3]+bb.w};
      *(float4*)(orow + ca) = val;
    }
    int cb = c0 + 64 + tx*4;
    if (cb < EV) {
      float4 bb = *(const float4*)(ff2_b + cb);
      float4 val = {acc[i][4]+bb.x, acc[i][5]+bb.y, acc[i][6]+bb.z, acc[i][7]+bb.w};
      *(float4*)(orow + cb) = val;
    }
  }
}

// ---------------- in-place row softmax ----------------
__global__ __launch_bounds__(256) void k_softmax(float* out) {
  int row = blockIdx.x, tid = threadIdx.x;
  float* p = out + (size_t)row*EV;
  float m = -1e30f, ssum = 0.f;
  for (int j = tid; j < EV; j += 256) {
    float x = p[j];
    if (x > m) { ssum = ssum*expf(m - x) + 1.f; m = x; }
    else ssum += expf(x - m);
  }
  __shared__ float sm[256], ss[256];
  sm[tid] = m; ss[tid] = ssum;
  __syncthreads();
  for (int st = 128; st >= 1; st >>= 1) {
    if (tid < st) {
      float m2 = sm[tid+st], s2 = ss[tid+st];
      float M = fmaxf(sm[tid], m2);
      ss[tid] = ss[tid]*expf(sm[tid]-M) + s2*expf(m2-M);
      sm[tid] = M;
    }
    __syncthreads();
  }
  float M = sm[0];
  float inv = 1.f/ss[0];
  for (int j = tid; j < EV; j += 256) {
    p[j] = expf(p[j] - M) * inv;
  }
}

extern "C" void kernel_launch(void* const* d_in, const int* in_sizes, int n_in,
                              void* d_out, int out_size, void* d_ws, size_t ws_size,
                              hipStream_t stream) {
  (void)in_sizes; (void)n_in; (void)out_size;
  const int*   enc_in  = (const int*)d_in[0];
  const float* femb    = (const float*)d_in[2];
  const float* enc_W   = (const float*)d_in[4];
  const float* enc_U   = (const float*)d_in[5];
  const float* enc_b   = (const float*)d_in[6];
  const float* dec_W   = (const float*)d_in[7];
  const float* dec_U   = (const float*)d_in[8];
  const float* dec_b   = (const float*)d_in[9];
  const float* att_W1  = (const float*)d_in[10];
  const float* att_W2  = (const float*)d_in[11];
  const float* sp1_W   = (const float*)d_in[12];
  const float* sp1_b   = (const float*)d_in[13];
  const float* sp2_W   = (const float*)d_in[14];
  const float* sp2_b   = (const float*)d_in[15];
  const float* ff1_W   = (const float*)d_in[16];
  const float* ff1_b   = (const float*)d_in[17];
  const float* ff2_W   = (const float*)d_in[18];
  const float* ff2_b   = (const float*)d_in[19];
  float* out = (float*)d_out;
  float* ws  = (float*)d_ws;

  float* enc_T  = ws + 0;          // 409600
  float* h_st   = ws + 409600;     // 6400
  float* rd_g   = ws + 416000;     // 6400
  float* h_g    = ws + 422400;     // 6400
  float* OUT_g  = ws + 428800;     // 64*1312 = 83968
  float* dec_o  = ws + 512768;     // 204800
  float* hid    = ws + 717568;     // 204800
  float* vbuf   = ws + 922368;     // 256
  float* c2buf  = ws + 922624;     // 32 (pad)
  unsigned* cnt = (unsigned*)(ws + 922656);  // 8192 uints (128B-padded counters)
  float* xs_all = ws + 930848;     // 1228800 (dead after k_enc)
  if (ws_size < (size_t)2159648*4) return;   // ~8.6 MB

  k_setup<<<2, 256, 0, stream>>>(sp2_W, sp2_b, vbuf, c2buf);
  k_embed<<<4096, 320, 0, stream>>>(enc_in, femb, enc_W, enc_b, xs_all);
  k_enc<<<64, 192, 0, stream>>>(enc_U, enc_b, xs_all, enc_T, h_st);
  hipMemsetAsync(cnt, 0, 8192*sizeof(unsigned), stream);
  k_coop<<<128, 512, 0, stream>>>(enc_T, h_st, dec_W, dec_U, dec_b, sp1_W, sp1_b,
                                  att_W1, att_W2, vbuf, c2buf,
                                  rd_g, h_g, OUT_g, dec_o, cnt);
  k_ff1<<<2048, 128, 0, stream>>>(dec_o, ff1_W, ff1_b, hid);
  k_logits<<<dim3(157, 16), 256, 0, stream>>>(hid, ff2_W, ff2_b, out);
  k_softmax<<<2048, 256, 0, stream>>>(out);
}

// Round 8
// 1451.857 us; speedup vs baseline: 1.2069x; 1.1161x over previous
//
#include <hip/hip_runtime.h>
#include <math.h>

#define B 64
#define TF 64
#define TE 32
#define E_DIM 40
#define H 100
#define H2 200
#define H3 300
#define SP 256
#define EV 20000
#define ROWS (B*TF)        // 4096
#define NC 1012            // Q cols: Psc200 | PY256 | Qdw300 | Qmid256

// ---------------- setup: W_all[k][c] packed projection matrix + v + c2 ----------------
__global__ __launch_bounds__(256) void k_setup(const float* att_W1, const float* dec_W,
        const float* sp1_W, const float* sp2_W, const float* sp2_b,
        float* W_all, float* v, float* c2) {
  int bid = blockIdx.x;
  if (bid < 396) {
    int idx = bid*256 + threadIdx.x;
    if (idx < 100*NC) {
      int k = idx / NC, c = idx - k*NC;
      float val;
      if (c < 200)      val = att_W1[(100+k)*H2 + c];          // attW1 bottom
      else if (c < 456) val = sp1_W[(200+k)*SP + (c-200)];     // sp1W enc-part
      else if (c < 756) val = dec_W[k*H3 + (c-456)];           // dec_W
      else              val = sp1_W[(100+k)*SP + (c-756)];     // sp1W rd-part
      W_all[idx] = val;
    }
  } else if (bid == 396) {
    int k = threadIdx.x;
    float s = 0.f;
    for (int j = 0; j < SP; ++j) s += sp2_W[k*SP + j];
    v[k] = s * (1.f/256.f);
  } else {
    if (threadIdx.x == 0) {
      float s = 0.f;
      for (int j = 0; j < SP; ++j) s += sp2_b[j];
      *c2 = s * (1.f/256.f);
    }
  }
}

// ---------------- encoder xs = embed @ enc_W + enc_b[0] ----------------
__global__ __launch_bounds__(320) void k_embed(const int* enc_in, const float* femb,
        const float* enc_W, const float* enc_b, float* xs_all) {
  int row = blockIdx.x;
  int j = threadIdx.x;
  __shared__ __align__(16) float emb[E_DIM];
  int tok = enc_in[row];
  if (j < E_DIM) emb[j] = femb[tok*E_DIM + j];
  __syncthreads();
  if (j < H3) {
    float acc = enc_b[j];
    #pragma unroll
    for (int k = 0; k < E_DIM; ++k) acc += emb[k]*enc_W[k*H3 + j];
    xs_all[row*H3 + j] = acc;
  }
}

// ---------------- encoder GRU recurrence ----------------
__global__ __launch_bounds__(192) void k_enc(const float* __restrict__ enc_U,
        const float* __restrict__ enc_b, const float* __restrict__ xs_all,
        float* __restrict__ enc_T, float* __restrict__ h_state) {
  int b = blockIdx.x, t = threadIdx.x;
  __shared__ __align__(16) float hsh[104];
  __shared__ __align__(16) float hs[304];

  float2 Ur[100];
  float2 bias = {0.f, 0.f};
  if (t < 150) {
    const float* base = enc_U + 2*t;
    #pragma unroll
    for (int k = 0; k < 100; ++k) Ur[k] = *(const float2*)(base + k*H3);
    bias = *(const float2*)(enc_b + H3 + 2*t);
  }
  if (t < H) hsh[t] = 0.f;
  __syncthreads();

  #pragma unroll 1
  for (int step = 0; step < TF; ++step) {
    int row = b*TF + step;
    float xz = 0.f, xr = 0.f, xh = 0.f;
    if (t < H) {
      xz = xs_all[row*H3 + t];
      xr = xs_all[row*H3 + 100 + t];
      xh = xs_all[row*H3 + 200 + t];
    }
    if (t < 150) {
      float a0 = bias.x, a1 = bias.y;
      const float4* h4 = (const float4*)hsh;
      #pragma unroll
      for (int k4 = 0; k4 < 25; ++k4) {
        float4 hv = h4[k4];
        a0 += hv.x*Ur[k4*4+0].x + hv.y*Ur[k4*4+1].x + hv.z*Ur[k4*4+2].x + hv.w*Ur[k4*4+3].x;
        a1 += hv.x*Ur[k4*4+0].y + hv.y*Ur[k4*4+1].y + hv.z*Ur[k4*4+2].y + hv.w*Ur[k4*4+3].y;
      }
      hs[2*t]   = a0;
      hs[2*t+1] = a1;
    }
    __syncthreads();
    if (t < H) {
      float z = 1.f/(1.f+expf(-(xz + hs[t])));
      float r = 1.f/(1.f+expf(-(xr + hs[100+t])));
      float cand = tanhf(xh + r*hs[200+t]);
      float hn = z*hsh[t] + (1.f-z)*cand;
      hsh[t] = hn;
      enc_T[t*ROWS + row] = hn;
    }
    __syncthreads();
  }
  if (t < H) h_state[b*H + t] = hsh[t];
}

// ---------------- Q init: [4096,100] @ [100,1012] tiled GEMM ----------------
#define KC 20
__global__ __launch_bounds__(256) void k_initQ(const float* __restrict__ enc_T,
        const float* __restrict__ W_all, float* __restrict__ Q_g) {
  int bx = blockIdx.x, by = blockIdx.y;
  int tid = threadIdx.x;
  int tx = tid & 15, ty = tid >> 4;
  __shared__ __align__(16) float At[KC*132];
  __shared__ __align__(16) float Wt[KC*132];
  int r0 = by*128;
  int c0 = bx*128;
  float acc[8][8];
  #pragma unroll
  for (int i = 0; i < 8; ++i)
    #pragma unroll
    for (int j = 0; j < 8; ++j) acc[i][j] = 0.f;
  for (int kc = 0; kc < 100; kc += KC) {
    __syncthreads();
    for (int i = tid; i < 128*KC; i += 256) {
      int r = i & 127, kk = i >> 7;
      At[kk*132 + r] = enc_T[(kc+kk)*ROWS + r0 + r];
    }
    for (int i = tid; i < 128*KC; i += 256) {
      int cidx = i & 127, kk = i >> 7;
      int gc = c0 + cidx;
      Wt[kk*132 + cidx] = (gc < NC) ? W_all[(kc+kk)*NC + gc] : 0.f;
    }
    __syncthreads();
    #pragma unroll
    for (int kk = 0; kk < KC; ++kk) {
      const float* Ar = At + kk*132;
      const float* Wr = Wt + kk*132;
      float4 a0 = *(const float4*)(Ar + ty*4);
      float4 a1 = *(const float4*)(Ar + 64 + ty*4);
      float4 w0 = *(const float4*)(Wr + tx*4);
      float4 w1 = *(const float4*)(Wr + 64 + tx*4);
      float av[8] = {a0.x,a0.y,a0.z,a0.w,a1.x,a1.y,a1.z,a1.w};
      float wv[8] = {w0.x,w0.y,w0.z,w0.w,w1.x,w1.y,w1.z,w1.w};
      #pragma unroll
      for (int i = 0; i < 8; ++i)
        #pragma unroll
        for (int j = 0; j < 8; ++j) acc[i][j] += av[i]*wv[j];
    }
  }
  #pragma unroll
  for (int i = 0; i < 8; ++i) {
    int r = r0 + ty*4 + (i < 4 ? i : 60 + i);
    float* orow = Q_g + (size_t)r*NC;
    int ca = c0 + tx*4;
    if (ca < NC) {
      float4 val = {acc[i][0], acc[i][1], acc[i][2], acc[i][3]};
      *(float4*)(orow + ca) = val;
    }
    int cb = c0 + 64 + tx*4;
    if (cb < NC) {
      float4 val = {acc[i][4], acc[i][5], acc[i][6], acc[i][7]};
      *(float4*)(orow + cb) = val;
    }
  }
}

// ---------------- decoder: 64 independent blocks, full projection-space state ----------
// Per batch: Psc/PY in LDS (row-wise score/gate ops); Qdw/Qmid in REGISTERS
// (column ownership: reductions over t thread-local, blends elementwise).
// enc and rd are never materialized. No cross-block communication at all.
__global__ __launch_bounds__(512, 1) void k_dec(
    const float* __restrict__ Q_g, const float* __restrict__ h_st,
    const float* __restrict__ dec_U, const float* __restrict__ dec_b,
    const float* __restrict__ sp1_W, const float* __restrict__ sp1_b,
    const float* __restrict__ att_W1, const float* __restrict__ att_W2,
    const float* __restrict__ v_g, const float* __restrict__ c2p,
    float* __restrict__ dec_o) {
  int b = blockIdx.x, tid = threadIdx.x;
  int w = tid >> 6, lane = tid & 63;
  __shared__ float Psc[64*200];             // 51.2 KB
  __shared__ float PYs[64*256];             // 65.5 KB
  __shared__ __align__(16) float Rsh[1016];
  __shared__ __align__(16) float hL[104];
  __shared__ float hWs[200], qs[200], ccs[256], vL[256], spb[256];
  __shared__ __align__(16) float dbs[600];
  __shared__ float xsx[304], hsx[304];
  __shared__ __align__(16) float scor[64];
  __shared__ __align__(16) float alph[64];
  __shared__ __align__(16) float gsh[64];

  float qd[64];   // Qdw col (456+tid), tid<300 — static indexing only
  float qm[64];   // Qmid col (756+tid), tid<256

  const float* Qb = Q_g + (size_t)b*64*NC;

  // ---- prologue: load state ----
  for (int i = tid; i < 12800; i += 512) {
    int t = i / 200, c = i - t*200;
    Psc[i] = Qb[t*NC + c];
  }
  for (int i = tid; i < 16384; i += 512) {
    int t = i >> 8, j = i & 255;
    PYs[i] = Qb[t*NC + 200 + j];
  }
  if (tid < 300) {
    #pragma unroll
    for (int t = 0; t < 64; ++t) qd[t] = Qb[t*NC + 456 + tid];
  }
  if (tid < 256) {
    #pragma unroll
    for (int t = 0; t < 64; ++t) qm[t] = Qb[t*NC + 756 + tid];
    vL[tid] = v_g[tid];
    spb[tid] = sp1_b[tid];
  }
  if (tid < 104) hL[tid] = (tid < 100) ? h_st[b*100 + tid] : 0.f;
  for (int i = tid; i < 600; i += 512) dbs[i] = dec_b[i];
  float c2 = *c2p;
  __syncthreads();
  // initial hW/q from h(-1)
  for (int cx = tid; cx < 400; cx += 512) {
    const float* Wm = (cx < 200) ? att_W1 : att_W2;
    int col = (cx < 200) ? cx : cx - 200;
    float a = 0.f;
    #pragma unroll 5
    for (int k = 0; k < 100; ++k) a += hL[k]*Wm[k*H2 + col];
    if (cx < 200) hWs[col] = a; else qs[col] = a;
  }
  __syncthreads();

  #pragma unroll 1
  for (int s = 0; s < TE; ++s) {
    // P0: scores_t = sum_c tanh(hW_c + Psc[t,c]) q_c
    #pragma unroll
    for (int i = 0; i < 8; ++i) {
      int t = w*8 + i;
      float sp = 0.f;
      for (int c = lane; c < 200; c += 64)
        sp += tanhf(hWs[c] + Psc[t*200 + c]) * qs[c];
      #pragma unroll
      for (int mk = 32; mk >= 1; mk >>= 1) sp += __shfl_xor(sp, mk);
      if (lane == 0) scor[t] = sp;
    }
    __syncthreads();
    // P1: softmax over t
    if (w == 0) {
      float sc = scor[lane];
      float m = sc;
      #pragma unroll
      for (int mk = 32; mk >= 1; mk >>= 1) m = fmaxf(m, __shfl_xor(m, mk));
      float ex = expf(sc - m);
      float ssum = ex;
      #pragma unroll
      for (int mk = 32; mk >= 1; mk >>= 1) ssum += __shfl_xor(ssum, mk);
      alph[lane] = ex / ssum;
    }
    __syncthreads();
    // P2: R = alpha @ Q  (reg cols thread-local; LDS cols by column scan)
    if (tid < 300) {
      float r = 0.f;
      #pragma unroll
      for (int t4 = 0; t4 < 16; ++t4) {
        float4 a4 = *(const float4*)(alph + t4*4);
        r += a4.x*qd[t4*4+0] + a4.y*qd[t4*4+1] + a4.z*qd[t4*4+2] + a4.w*qd[t4*4+3];
      }
      Rsh[456 + tid] = r;
    }
    if (tid < 256) {
      float r = 0.f;
      #pragma unroll
      for (int t4 = 0; t4 < 16; ++t4) {
        float4 a4 = *(const float4*)(alph + t4*4);
        r += a4.x*qm[t4*4+0] + a4.y*qm[t4*4+1] + a4.z*qm[t4*4+2] + a4.w*qm[t4*4+3];
      }
      Rsh[756 + tid] = r;
      float rp = 0.f;
      #pragma unroll 8
      for (int t = 0; t < 64; ++t) rp += alph[t]*PYs[t*256 + tid];
      Rsh[200 + tid] = rp;
    } else if (tid >= 300 && tid < 500) {
      int c = tid - 300;
      float rs = 0.f;
      #pragma unroll 8
      for (int t = 0; t < 64; ++t) rs += alph[t]*Psc[t*200 + c];
      Rsh[c] = rs;
    }
    __syncthreads();
    // P3: xs = R_dw + b0 ; hs = h @ dec_U + b1  (dec_U L2-resident)
    if (tid < 300) {
      float a = dbs[300 + tid];
      #pragma unroll 5
      for (int k = 0; k < 100; ++k) a += hL[k]*dec_U[k*H3 + tid];
      hsx[tid] = a;
      xsx[tid] = Rsh[456 + tid] + dbs[tid];
    }
    __syncthreads();
    if (tid < 100) {
      float xz = xsx[tid], xr = xsx[100+tid], xh = xsx[200+tid];
      float hz = hsx[tid], hr = hsx[100+tid], hh = hsx[200+tid];
      float hv = hL[tid];
      float z = 1.f/(1.f+expf(-(xz+hz)));
      float r = 1.f/(1.f+expf(-(xr+hr)));
      float cand = tanhf(xh + r*hh);
      float hn = z*hv + (1.f-z)*cand;
      hL[tid] = hn;
      dec_o[(b*TE + s)*H + tid] = hn;
    }
    __syncthreads();
    // P4: cc_h = h_new @ sp1W[0:100] ; hW/q = h_new @ [attW1top | attW2]
    for (int cx = tid; cx < 656; cx += 512) {
      if (cx < 256) {
        float a = 0.f;
        #pragma unroll 5
        for (int k = 0; k < 100; ++k) a += hL[k]*sp1_W[k*SP + cx];
        ccs[cx] = a + Rsh[756 + cx] + spb[cx];
      } else {
        int cy = cx - 256;
        const float* Wm = (cy < 200) ? att_W1 : att_W2;
        int col = (cy < 200) ? cy : cy - 200;
        float a = 0.f;
        #pragma unroll 5
        for (int k = 0; k < 100; ++k) a += hL[k]*Wm[k*H2 + col];
        if (cy < 200) hWs[col] = a; else qs[col] = a;
      }
    }
    __syncthreads();
    // P5: gate g_t = sigmoid( sum_j relu(cc_j + PY[t,j]) v_j + c2 )
    #pragma unroll
    for (int i = 0; i < 8; ++i) {
      int t = w*8 + i;
      float gp = 0.f;
      #pragma unroll
      for (int jj = 0; jj < 4; ++jj) {
        int j = lane + jj*64;
        gp += fmaxf(ccs[j] + PYs[t*256 + j], 0.f) * vL[j];
      }
      #pragma unroll
      for (int mk = 32; mk >= 1; mk >>= 1) gp += __shfl_xor(gp, mk);
      if (lane == 0) gsh[t] = 1.f/(1.f+expf(-(gp + c2)));
    }
    __syncthreads();
    // P6: blend all projections: Q' = g*Q + (1-g)*R
    for (int i = tid; i < 12800; i += 512) {
      int t = i / 200, c = i - t*200;
      float g = gsh[t];
      Psc[i] = g*Psc[i] + (1.f-g)*Rsh[c];
    }
    for (int i = tid; i < 16384; i += 512) {
      int t = i >> 8, j = i & 255;
      float g = gsh[t];
      PYs[i] = g*PYs[i] + (1.f-g)*Rsh[200 + j];
    }
    if (tid < 300) {
      float rv = Rsh[456 + tid];
      #pragma unroll
      for (int t4 = 0; t4 < 16; ++t4) {
        float4 g4 = *(const float4*)(gsh + t4*4);
        qd[t4*4+0] = g4.x*qd[t4*4+0] + (1.f-g4.x)*rv;
        qd[t4*4+1] = g4.y*qd[t4*4+1] + (1.f-g4.y)*rv;
        qd[t4*4+2] = g4.z*qd[t4*4+2] + (1.f-g4.z)*rv;
        qd[t4*4+3] = g4.w*qd[t4*4+3] + (1.f-g4.w)*rv;
      }
    }
    if (tid < 256) {
      float rv = Rsh[756 + tid];
      #pragma unroll
      for (int t4 = 0; t4 < 16; ++t4) {
        float4 g4 = *(const float4*)(gsh + t4*4);
        qm[t4*4+0] = g4.x*qm[t4*4+0] + (1.f-g4.x)*rv;
        qm[t4*4+1] = g4.y*qm[t4*4+1] + (1.f-g4.y)*rv;
        qm[t4*4+2] = g4.z*qm[t4*4+2] + (1.f-g4.z)*rv;
        qm[t4*4+3] = g4.w*qm[t4*4+3] + (1.f-g4.w)*rv;
      }
    }
    __syncthreads();
  }
}

// ---------------- ff1: hid = relu(dec_out @ ff1_W + b) ----------------
__global__ __launch_bounds__(128) void k_ff1(const float* dec_out, const float* ff1_W,
        const float* ff1_b, float* hid) {
  int row = blockIdx.x, j = threadIdx.x;
  __shared__ __align__(16) float a[104];
  if (j < H) a[j] = dec_out[row*H + j];
  __syncthreads();
  if (j < H) {
    float acc = ff1_b[j];
    const float4* a4 = (const float4*)a;
    #pragma unroll
    for (int k4 = 0; k4 < 25; ++k4) {
      float4 av = a4[k4];
      int k = k4*4;
      acc += av.x*ff1_W[(k+0)*H+j] + av.y*ff1_W[(k+1)*H+j] + av.z*ff1_W[(k+2)*H+j] + av.w*ff1_W[(k+3)*H+j];
    }
    hid[row*H + j] = fmaxf(acc, 0.f);
  }
}

// ---------------- logits GEMM: [2048,100] x [100,20000] ----------------
__global__ __launch_bounds__(256) void k_logits(const float* hid, const float* ff2_W,
        const float* ff2_b, float* out) {
  int bx = blockIdx.x, by = blockIdx.y;
  int tid = threadIdx.x;
  int tx = tid & 15, ty = tid >> 4;
  __shared__ __align__(16) float At[KC*132];
  __shared__ __align__(16) float Wt[KC*132];
  int r0 = by*128;
  int c0 = bx*128;
  float acc[8][8];
  #pragma unroll
  for (int i = 0; i < 8; ++i) {
    #pragma unroll
    for (int j = 0; j < 8; ++j) acc[i][j] = 0.f;
  }
  for (int kc = 0; kc < 100; kc += KC) {
    __syncthreads();
    for (int i = tid; i < 128*KC; i += 256) {
      int r = i & 127, kk = i >> 7;
      At[kk*132 + r] = hid[(r0+r)*H + kc + kk];
    }
    for (int i = tid; i < 128*KC; i += 256) {
      int cidx = i & 127, kk = i >> 7;
      int gc = c0 + cidx;
      Wt[kk*132 + cidx] = (gc < EV) ? ff2_W[(size_t)(kc+kk)*EV + gc] : 0.f;
    }
    __syncthreads();
    #pragma unroll
    for (int kk = 0; kk < KC; ++kk) {
      const float* Ar = At + kk*132;
      const float* Wr = Wt + kk*132;
      float4 a0 = *(const float4*)(Ar + ty*4);
      float4 a1 = *(const float4*)(Ar + 64 + ty*4);
      float4 w0 = *(const float4*)(Wr + tx*4);
      float4 w1 = *(const float4*)(Wr + 64 + tx*4);
      float av[8] = {a0.x,a0.y,a0.z,a0.w,a1.x,a1.y,a1.z,a1.w};
      float wv[8] = {w0.x,w0.y,w0.z,w0.w,w1.x,w1.y,w1.z,w1.w};
      #pragma unroll
      for (int i = 0; i < 8; ++i) {
        #pragma unroll
        for (int j = 0; j < 8; ++j) acc[i][j] += av[i]*wv[j];
      }
    }
  }
  #pragma unroll
  for (int i = 0; i < 8; ++i) {
    int r = r0 + ty*4 + (i < 4 ? i : 60 + i);
    float* orow = out + (size_t)r*EV;
    int ca = c0 + tx*4;
    if (ca < EV) {
      float4 bb = *(const float4*)(ff2_b + ca);
      float4 val = {acc[i][0]+bb.x, acc[i][1]+bb.y, acc[i][2]+bb.z, acc[i][3]+bb.w};
      *(float4*)(orow + ca) = val;
    }
    int cb = c0 + 64 + tx*4;
    if (cb < EV) {
      float4 bb = *(const float4*)(ff2_b + cb);
      float4 val = {acc[i][4]+bb.x, acc[i][5]+bb.y, acc[i][6]+bb.z, acc[i][7]+bb.w};
      *(float4*)(orow + cb) = val;
    }
  }
}

// ---------------- in-place row softmax ----------------
__global__ __launch_bounds__(256) void k_softmax(float* out) {
  int row = blockIdx.x, tid = threadIdx.x;
  float* p = out + (size_t)row*EV;
  float m = -1e30f, ssum = 0.f;
  for (int j = tid; j < EV; j += 256) {
    float x = p[j];
    if (x > m) { ssum = ssum*expf(m - x) + 1.f; m = x; }
    else ssum += expf(x - m);
  }
  __shared__ float sm[256], ss[256];
  sm[tid] = m; ss[tid] = ssum;
  __syncthreads();
  for (int st = 128; st >= 1; st >>= 1) {
    if (tid < st) {
      float m2 = sm[tid+st], s2 = ss[tid+st];
      float M = fmaxf(sm[tid], m2);
      ss[tid] = ss[tid]*expf(sm[tid]-M) + s2*expf(m2-M);
      sm[tid] = M;
    }
    __syncthreads();
  }
  float M = sm[0];
  float inv = 1.f/ss[0];
  for (int j = tid; j < EV; j += 256) {
    p[j] = expf(p[j] - M) * inv;
  }
}

extern "C" void kernel_launch(void* const* d_in, const int* in_sizes, int n_in,
                              void* d_out, int out_size, void* d_ws, size_t ws_size,
                              hipStream_t stream) {
  (void)in_sizes; (void)n_in; (void)out_size;
  const int*   enc_in  = (const int*)d_in[0];
  const float* femb    = (const float*)d_in[2];
  const float* enc_W   = (const float*)d_in[4];
  const float* enc_U   = (const float*)d_in[5];
  const float* enc_b   = (const float*)d_in[6];
  const float* dec_W   = (const float*)d_in[7];
  const float* dec_U   = (const float*)d_in[8];
  const float* dec_b   = (const float*)d_in[9];
  const float* att_W1  = (const float*)d_in[10];
  const float* att_W2  = (const float*)d_in[11];
  const float* sp1_W   = (const float*)d_in[12];
  const float* sp1_b   = (const float*)d_in[13];
  const float* sp2_W   = (const float*)d_in[14];
  const float* sp2_b   = (const float*)d_in[15];
  const float* ff1_W   = (const float*)d_in[16];
  const float* ff1_b   = (const float*)d_in[17];
  const float* ff2_W   = (const float*)d_in[18];
  const float* ff2_b   = (const float*)d_in[19];
  float* out = (float*)d_out;
  float* ws  = (float*)d_ws;

  float* enc_T  = ws + 0;          // 409600
  float* W_all  = ws + 409600;     // 100*1012 = 101200
  float* h_st   = ws + 510800;     // 6400
  float* dec_o  = ws + 517200;     // 204800
  float* hid    = ws + 722000;     // 204800
  float* vbuf   = ws + 926800;     // 256
  float* c2buf  = ws + 927056;     // 16 (pad)
  float* Q_g    = ws + 927072;     // 4096*1012 = 4145152
  float* xs_all = Q_g;             // aliases Q_g (dead after k_enc, before k_initQ)
  if (ws_size < (size_t)5072224*4) return;   // ~20.3 MB

  k_setup<<<398, 256, 0, stream>>>(att_W1, dec_W, sp1_W, sp2_W, sp2_b, W_all, vbuf, c2buf);
  k_embed<<<4096, 320, 0, stream>>>(enc_in, femb, enc_W, enc_b, xs_all);
  k_enc<<<64, 192, 0, stream>>>(enc_U, enc_b, xs_all, enc_T, h_st);
  k_initQ<<<dim3(8, 32), 256, 0, stream>>>(enc_T, W_all, Q_g);
  k_dec<<<64, 512, 0, stream>>>(Q_g, h_st, dec_U, dec_b, sp1_W, sp1_b,
                                att_W1, att_W2, vbuf, c2buf, dec_o);
  k_ff1<<<2048, 128, 0, stream>>>(dec_o, ff1_W, ff1_b, hid);
  k_logits<<<dim3(157, 16), 256, 0, stream>>>(hid, ff2_W, ff2_b, out);
  k_softmax<<<2048, 256, 0, stream>>>(out);
}

// Round 10
// 1302.935 us; speedup vs baseline: 1.3448x; 1.1143x over previous
//
#include <hip/hip_runtime.h>
#include <math.h>

#define B 64
#define TF 64
#define TE 32
#define E_DIM 40
#define H 100
#define H2 200
#define H3 300
#define SP 256
#define EV 20000
#define ROWS (B*TF)        // 4096
#define NC 1012            // Q cols: Psc200 | PY256 | Qdw300 | Qmid256

// ---------------- setup: W_all[k][c] packed projection matrix + v + c2 ----------------
__global__ __launch_bounds__(256) void k_setup(const float* att_W1, const float* dec_W,
        const float* sp1_W, const float* sp2_W, const float* sp2_b,
        float* W_all, float* v, float* c2) {
  int bid = blockIdx.x;
  if (bid < 396) {
    int idx = bid*256 + threadIdx.x;
    if (idx < 100*NC) {
      int k = idx / NC, c = idx - k*NC;
      float val;
      if (c < 200)      val = att_W1[(100+k)*H2 + c];          // attW1 bottom
      else if (c < 456) val = sp1_W[(200+k)*SP + (c-200)];     // sp1W enc-part
      else if (c < 756) val = dec_W[k*H3 + (c-456)];           // dec_W
      else              val = sp1_W[(100+k)*SP + (c-756)];     // sp1W rd-part
      W_all[idx] = val;
    }
  } else if (bid == 396) {
    int k = threadIdx.x;
    float s = 0.f;
    for (int j = 0; j < SP; ++j) s += sp2_W[k*SP + j];
    v[k] = s * (1.f/256.f);
  } else {
    if (threadIdx.x == 0) {
      float s = 0.f;
      for (int j = 0; j < SP; ++j) s += sp2_b[j];
      *c2 = s * (1.f/256.f);
    }
  }
}

// ---------------- encoder xs = embed @ enc_W + enc_b[0] ----------------
__global__ __launch_bounds__(320) void k_embed(const int* enc_in, const float* femb,
        const float* enc_W, const float* enc_b, float* xs_all) {
  int row = blockIdx.x;
  int j = threadIdx.x;
  __shared__ __align__(16) float emb[E_DIM];
  int tok = enc_in[row];
  if (j < E_DIM) emb[j] = femb[tok*E_DIM + j];
  __syncthreads();
  if (j < H3) {
    float acc = enc_b[j];
    #pragma unroll
    for (int k = 0; k < E_DIM; ++k) acc += emb[k]*enc_W[k*H3 + j];
    xs_all[row*H3 + j] = acc;
  }
}

// ---------------- encoder GRU recurrence ----------------
__global__ __launch_bounds__(192) void k_enc(const float* __restrict__ enc_U,
        const float* __restrict__ enc_b, const float* __restrict__ xs_all,
        float* __restrict__ enc_T, float* __restrict__ h_state) {
  int b = blockIdx.x, t = threadIdx.x;
  __shared__ __align__(16) float hsh[104];
  __shared__ __align__(16) float hs[304];

  float2 Ur[100];
  float2 bias = {0.f, 0.f};
  if (t < 150) {
    const float* base = enc_U + 2*t;
    #pragma unroll
    for (int k = 0; k < 100; ++k) Ur[k] = *(const float2*)(base + k*H3);
    bias = *(const float2*)(enc_b + H3 + 2*t);
  }
  if (t < H) hsh[t] = 0.f;
  __syncthreads();

  #pragma unroll 1
  for (int step = 0; step < TF; ++step) {
    int row = b*TF + step;
    float xz = 0.f, xr = 0.f, xh = 0.f;
    if (t < H) {
      xz = xs_all[row*H3 + t];
      xr = xs_all[row*H3 + 100 + t];
      xh = xs_all[row*H3 + 200 + t];
    }
    if (t < 150) {
      float a0 = bias.x, a1 = bias.y;
      const float4* h4 = (const float4*)hsh;
      #pragma unroll
      for (int k4 = 0; k4 < 25; ++k4) {
        float4 hv = h4[k4];
        a0 += hv.x*Ur[k4*4+0].x + hv.y*Ur[k4*4+1].x + hv.z*Ur[k4*4+2].x + hv.w*Ur[k4*4+3].x;
        a1 += hv.x*Ur[k4*4+0].y + hv.y*Ur[k4*4+1].y + hv.z*Ur[k4*4+2].y + hv.w*Ur[k4*4+3].y;
      }
      hs[2*t]   = a0;
      hs[2*t+1] = a1;
    }
    __syncthreads();
    if (t < H) {
      float z = 1.f/(1.f+expf(-(xz + hs[t])));
      float r = 1.f/(1.f+expf(-(xr + hs[100+t])));
      float cand = tanhf(xh + r*hs[200+t]);
      float hn = z*hsh[t] + (1.f-z)*cand;
      hsh[t] = hn;
      enc_T[t*ROWS + row] = hn;
    }
    __syncthreads();
  }
  if (t < H) h_state[b*H + t] = hsh[t];
}

// ---------------- Q init: [4096,100] @ [100,1012] tiled GEMM ----------------
#define KC 20
__global__ __launch_bounds__(256) void k_initQ(const float* __restrict__ enc_T,
        const float* __restrict__ W_all, float* __restrict__ Q_g) {
  int bx = blockIdx.x, by = blockIdx.y;
  int tid = threadIdx.x;
  int tx = tid & 15, ty = tid >> 4;
  __shared__ __align__(16) float At[KC*132];
  __shared__ __align__(16) float Wt[KC*132];
  int r0 = by*128;
  int c0 = bx*128;
  float acc[8][8];
  #pragma unroll
  for (int i = 0; i < 8; ++i)
    #pragma unroll
    for (int j = 0; j < 8; ++j) acc[i][j] = 0.f;
  for (int kc = 0; kc < 100; kc += KC) {
    __syncthreads();
    for (int i = tid; i < 128*KC; i += 256) {
      int r = i & 127, kk = i >> 7;
      At[kk*132 + r] = enc_T[(kc+kk)*ROWS + r0 + r];
    }
    for (int i = tid; i < 128*KC; i += 256) {
      int cidx = i & 127, kk = i >> 7;
      int gc = c0 + cidx;
      Wt[kk*132 + cidx] = (gc < NC) ? W_all[(kc+kk)*NC + gc] : 0.f;
    }
    __syncthreads();
    #pragma unroll
    for (int kk = 0; kk < KC; ++kk) {
      const float* Ar = At + kk*132;
      const float* Wr = Wt + kk*132;
      float4 a0 = *(const float4*)(Ar + ty*4);
      float4 a1 = *(const float4*)(Ar + 64 + ty*4);
      float4 w0 = *(const float4*)(Wr + tx*4);
      float4 w1 = *(const float4*)(Wr + 64 + tx*4);
      float av[8] = {a0.x,a0.y,a0.z,a0.w,a1.x,a1.y,a1.z,a1.w};
      float wv[8] = {w0.x,w0.y,w0.z,w0.w,w1.x,w1.y,w1.z,w1.w};
      #pragma unroll
      for (int i = 0; i < 8; ++i)
        #pragma unroll
        for (int j = 0; j < 8; ++j) acc[i][j] += av[i]*wv[j];
    }
  }
  #pragma unroll
  for (int i = 0; i < 8; ++i) {
    int r = r0 + ty*4 + (i < 4 ? i : 60 + i);
    float* orow = Q_g + (size_t)r*NC;
    int ca = c0 + tx*4;
    if (ca < NC) {
      float4 val = {acc[i][0], acc[i][1], acc[i][2], acc[i][3]};
      *(float4*)(orow + ca) = val;
    }
    int cb = c0 + 64 + tx*4;
    if (cb < NC) {
      float4 val = {acc[i][4], acc[i][5], acc[i][6], acc[i][7]};
      *(float4*)(orow + cb) = val;
    }
  }
}

// ---------------- decoder: 64 independent blocks, projection-space state ----------
// Psc/PY in LDS; Qdw+Qmid(212) as 16 NAMED float4 per thread (one column/thread;
// static member access only -> cannot be demoted to scratch). Qmid cols 212..255
// in LDS (Qex). No cross-block communication, no atomics, no inline asm.
#define Q16(OP) OP(0) OP(1) OP(2) OP(3) OP(4) OP(5) OP(6) OP(7) \
                OP(8) OP(9) OP(10) OP(11) OP(12) OP(13) OP(14) OP(15)
__global__ __launch_bounds__(512, 1) void k_dec(
    const float* __restrict__ Q_g, const float* __restrict__ h_st,
    const float* __restrict__ dec_U, const float* __restrict__ dec_b,
    const float* __restrict__ sp1_W, const float* __restrict__ sp1_b,
    const float* __restrict__ att_W1, const float* __restrict__ att_W2,
    const float* __restrict__ v_g, const float* __restrict__ c2p,
    float* __restrict__ dec_o) {
  int b = blockIdx.x, tid = threadIdx.x;
  int w = tid >> 6, lane = tid & 63;
  __shared__ float Psc[64*200];             // 51.2 KB
  __shared__ float PYs[64*256];             // 65.5 KB
  __shared__ float Qex[64*44];              // 11.3 KB (Qmid cols 212..255, t-major)
  __shared__ __align__(16) float Rsh[1016];
  __shared__ __align__(16) float hL[104];
  __shared__ float hWs[200], qs[200], ccs[256], vL[256], spb[256];
  __shared__ __align__(16) float dbs[600];
  __shared__ float xsx[304], hsx[304];
  __shared__ __align__(16) float scor[64];
  __shared__ __align__(16) float alph[64];
  __shared__ __align__(16) float gsh[64];

  // one Q column per thread: tid<300 -> Qdw col 456+tid ; else Qmid col 756+(tid-300)
  int mycol = (tid < 300) ? (456 + tid) : (756 + (tid - 300));
  const float* Qb = Q_g + (size_t)b*64*NC;

#define DECLQ(i) float4 q##i;
  Q16(DECLQ)

  // ---- prologue: load state ----
#define LOADQ(i) q##i = make_float4(Qb[(4*i+0)*NC + mycol], Qb[(4*i+1)*NC + mycol], \
                                    Qb[(4*i+2)*NC + mycol], Qb[(4*i+3)*NC + mycol]);
  Q16(LOADQ)
  for (int i = tid; i < 12800; i += 512) {
    int t = i / 200, c = i - t*200;
    Psc[i] = Qb[t*NC + c];
  }
  for (int i = tid; i < 16384; i += 512) {
    int t = i >> 8, j = i & 255;
    PYs[i] = Qb[t*NC + 200 + j];
  }
  for (int i = tid; i < 2816; i += 512) {
    int t = i / 44, e = i - t*44;
    Qex[i] = Qb[t*NC + 968 + e];
  }
  if (tid < 256) { vL[tid] = v_g[tid]; spb[tid] = sp1_b[tid]; }
  if (tid < 104) hL[tid] = (tid < 100) ? h_st[b*100 + tid] : 0.f;
  for (int i = tid; i < 600; i += 512) dbs[i] = dec_b[i];
  float c2 = *c2p;
  __syncthreads();
  // initial hW/q from h(-1)
  for (int cx = tid; cx < 400; cx += 512) {
    const float* Wm = (cx < 200) ? att_W1 : att_W2;
    int col = (cx < 200) ? cx : cx - 200;
    float a = 0.f;
    #pragma unroll 5
    for (int k = 0; k < 100; ++k) a += hL[k]*Wm[k*H2 + col];
    if (cx < 200) hWs[col] = a; else qs[col] = a;
  }
  __syncthreads();

  #pragma unroll 1
  for (int s = 0; s < TE; ++s) {
    // P0: scores_t = sum_c tanh(hW_c + Psc[t,c]) q_c
    #pragma unroll
    for (int i = 0; i < 8; ++i) {
      int t = w*8 + i;
      float sp = 0.f;
      for (int c = lane; c < 200; c += 64)
        sp += tanhf(hWs[c] + Psc[t*200 + c]) * qs[c];
      #pragma unroll
      for (int mk = 32; mk >= 1; mk >>= 1) sp += __shfl_xor(sp, mk);
      if (lane == 0) scor[t] = sp;
    }
    __syncthreads();
    // P1: softmax over t
    if (w == 0) {
      float sc = scor[lane];
      float m = sc;
      #pragma unroll
      for (int mk = 32; mk >= 1; mk >>= 1) m = fmaxf(m, __shfl_xor(m, mk));
      float ex = expf(sc - m);
      float ssum = ex;
      #pragma unroll
      for (int mk = 32; mk >= 1; mk >>= 1) ssum += __shfl_xor(ssum, mk);
      alph[lane] = ex / ssum;
    }
    __syncthreads();
    // P2: R = alpha @ Q  (own reg column + LDS column scans)
    {
      float rr = 0.f;
#define REDQ(i) rr += alph[4*i+0]*q##i.x + alph[4*i+1]*q##i.y \
                    + alph[4*i+2]*q##i.z + alph[4*i+3]*q##i.w;
      Q16(REDQ)
      Rsh[mycol] = rr;
    }
    if (tid < 200) {
      float rs = 0.f;
      #pragma unroll 8
      for (int t = 0; t < 64; ++t) rs += alph[t]*Psc[t*200 + tid];
      Rsh[tid] = rs;
    } else if (tid < 456) {
      int j = tid - 200;
      float rp = 0.f;
      #pragma unroll 8
      for (int t = 0; t < 64; ++t) rp += alph[t]*PYs[t*256 + j];
      Rsh[tid] = rp;
    } else if (tid < 500) {
      int e = tid - 456;
      float re = 0.f;
      #pragma unroll 8
      for (int t = 0; t < 64; ++t) re += alph[t]*Qex[t*44 + e];
      Rsh[968 + e] = re;
    }
    __syncthreads();
    // P3: xs = R_dw + b0 ; hs = h @ dec_U + b1  (dec_U L2-resident)
    if (tid < 300) {
      float a = dbs[300 + tid];
      #pragma unroll 5
      for (int k = 0; k < 100; ++k) a += hL[k]*dec_U[k*H3 + tid];
      hsx[tid] = a;
      xsx[tid] = Rsh[456 + tid] + dbs[tid];
    }
    __syncthreads();
    if (tid < 100) {
      float xz = xsx[tid], xr = xsx[100+tid], xh = xsx[200+tid];
      float hz = hsx[tid], hr = hsx[100+tid], hh = hsx[200+tid];
      float hv = hL[tid];
      float z = 1.f/(1.f+expf(-(xz+hz)));
      float r = 1.f/(1.f+expf(-(xr+hr)));
      float cand = tanhf(xh + r*hh);
      float hn = z*hv + (1.f-z)*cand;
      hL[tid] = hn;
      dec_o[(b*TE + s)*H + tid] = hn;
    }
    __syncthreads();
    // P4: cc_h = h_new @ sp1W[0:100] ; hW/q = h_new @ [attW1top | attW2]
    for (int cx = tid; cx < 656; cx += 512) {
      if (cx < 256) {
        float a = 0.f;
        #pragma unroll 5
        for (int k = 0; k < 100; ++k) a += hL[k]*sp1_W[k*SP + cx];
        ccs[cx] = a + Rsh[756 + cx] + spb[cx];
      } else {
        int cy = cx - 256;
        const float* Wm = (cy < 200) ? att_W1 : att_W2;
        int col = (cy < 200) ? cy : cy - 200;
        float a = 0.f;
        #pragma unroll 5
        for (int k = 0; k < 100; ++k) a += hL[k]*Wm[k*H2 + col];
        if (cy < 200) hWs[col] = a; else qs[col] = a;
      }
    }
    __syncthreads();
    // P5: gate g_t = sigmoid( sum_j relu(cc_j + PY[t,j]) v_j + c2 )
    #pragma unroll
    for (int i = 0; i < 8; ++i) {
      int t = w*8 + i;
      float gp = 0.f;
      #pragma unroll
      for (int jj = 0; jj < 4; ++jj) {
        int j = lane + jj*64;
        gp += fmaxf(ccs[j] + PYs[t*256 + j], 0.f) * vL[j];
      }
      #pragma unroll
      for (int mk = 32; mk >= 1; mk >>= 1) gp += __shfl_xor(gp, mk);
      if (lane == 0) gsh[t] = 1.f/(1.f+expf(-(gp + c2)));
    }
    __syncthreads();
    // P6: blend all projections: Q' = g*Q + (1-g)*R
    {
      float rv = Rsh[mycol];
#define BLDQ(i) { float g0 = gsh[4*i+0], g1 = gsh[4*i+1], g2 = gsh[4*i+2], g3 = gsh[4*i+3]; \
      q##i.x = g0*q##i.x + (1.f-g0)*rv;  q##i.y = g1*q##i.y + (1.f-g1)*rv; \
      q##i.z = g2*q##i.z + (1.f-g2)*rv;  q##i.w = g3*q##i.w + (1.f-g3)*rv; }
      Q16(BLDQ)
    }
    for (int i = tid; i < 12800; i += 512) {
      int t = i / 200, c = i - t*200;
      float g = gsh[t];
      Psc[i] = g*Psc[i] + (1.f-g)*Rsh[c];
    }
    for (int i = tid; i < 16384; i += 512) {
      int t = i >> 8, j = i & 255;
      float g = gsh[t];
      PYs[i] = g*PYs[i] + (1.f-g)*Rsh[200 + j];
    }
    for (int i = tid; i < 2816; i += 512) {
      int t = i / 44, e = i - t*44;
      float g = gsh[t];
      Qex[i] = g*Qex[i] + (1.f-g)*Rsh[968 + e];
    }
    __syncthreads();
  }
}

// ---------------- ff1: hid = relu(dec_out @ ff1_W + b) ----------------
__global__ __launch_bounds__(128) void k_ff1(const float* dec_out, const float* ff1_W,
        const float* ff1_b, float* hid) {
  int row = blockIdx.x, j = threadIdx.x;
  __shared__ __align__(16) float a[104];
  if (j < H) a[j] = dec_out[row*H + j];
  __syncthreads();
  if (j < H) {
    float acc = ff1_b[j];
    const float4* a4 = (const float4*)a;
    #pragma unroll
    for (int k4 = 0; k4 < 25; ++k4) {
      float4 av = a4[k4];
      int k = k4*4;
      acc += av.x*ff1_W[(k+0)*H+j] + av.y*ff1_W[(k+1)*H+j] + av.z*ff1_W[(k+2)*H+j] + av.w*ff1_W[(k+3)*H+j];
    }
    hid[row*H + j] = fmaxf(acc, 0.f);
  }
}

// ---------------- logits GEMM: [2048,100] x [100,20000] ----------------
__global__ __launch_bounds__(256) void k_logits(const float* hid, const float* ff2_W,
        const float* ff2_b, float* out) {
  int bx = blockIdx.x, by = blockIdx.y;
  int tid = threadIdx.x;
  int tx = tid & 15, ty = tid >> 4;
  __shared__ __align__(16) float At[KC*132];
  __shared__ __align__(16) float Wt[KC*132];
  int r0 = by*128;
  int c0 = bx*128;
  float acc[8][8];
  #pragma unroll
  for (int i = 0; i < 8; ++i) {
    #pragma unroll
    for (int j = 0; j < 8; ++j) acc[i][j] = 0.f;
  }
  for (int kc = 0; kc < 100; kc += KC) {
    __syncthreads();
    for (int i = tid; i < 128*KC; i += 256) {
      int r = i & 127, kk = i >> 7;
      At[kk*132 + r] = hid[(r0+r)*H + kc + kk];
    }
    for (int i = tid; i < 128*KC; i += 256) {
      int cidx = i & 127, kk = i >> 7;
      int gc = c0 + cidx;
      Wt[kk*132 + cidx] = (gc < EV) ? ff2_W[(size_t)(kc+kk)*EV + gc] : 0.f;
    }
    __syncthreads();
    #pragma unroll
    for (int kk = 0; kk < KC; ++kk) {
      const float* Ar = At + kk*132;
      const float* Wr = Wt + kk*132;
      float4 a0 = *(const float4*)(Ar + ty*4);
      float4 a1 = *(const float4*)(Ar + 64 + ty*4);
      float4 w0 = *(const float4*)(Wr + tx*4);
      float4 w1 = *(const float4*)(Wr + 64 + tx*4);
      float av[8] = {a0.x,a0.y,a0.z,a0.w,a1.x,a1.y,a1.z,a1.w};
      float wv[8] = {w0.x,w0.y,w0.z,w0.w,w1.x,w1.y,w1.z,w1.w};
      #pragma unroll
      for (int i = 0; i < 8; ++i) {
        #pragma unroll
        for (int j = 0; j < 8; ++j) acc[i][j] += av[i]*wv[j];
      }
    }
  }
  #pragma unroll
  for (int i = 0; i < 8; ++i) {
    int r = r0 + ty*4 + (i < 4 ? i : 60 + i);
    float* orow = out + (size_t)r*EV;
    int ca = c0 + tx*4;
    if (ca < EV) {
      float4 bb = *(const float4*)(ff2_b + ca);
      float4 val = {acc[i][0]+bb.x, acc[i][1]+bb.y, acc[i][2]+bb.z, acc[i][3]+bb.w};
      *(float4*)(orow + ca) = val;
    }
    int cb = c0 + 64 + tx*4;
    if (cb < EV) {
      float4 bb = *(const float4*)(ff2_b + cb);
      float4 val = {acc[i][4]+bb.x, acc[i][5]+bb.y, acc[i][6]+bb.z, acc[i][7]+bb.w};
      *(float4*)(orow + cb) = val;
    }
  }
}

// ---------------- in-place row softmax ----------------
__global__ __launch_bounds__(256) void k_softmax(float* out) {
  int row = blockIdx.x, tid = threadIdx.x;
  float* p = out + (size_t)row*EV;
  float m = -1e30f, ssum = 0.f;
  for (int j = tid; j < EV; j += 256) {
    float x = p[j];
    if (x > m) { ssum = ssum*expf(m - x) + 1.f; m = x; }
    else ssum += expf(x - m);
  }
  __shared__ float sm[256], ss[256];
  sm[tid] = m; ss[tid] = ssum;
  __syncthreads();
  for (int st = 128; st >= 1; st >>= 1) {
    if (tid < st) {
      float m2 = sm[tid+st], s2 = ss[tid+st];
      float M = fmaxf(sm[tid], m2);
      ss[tid] = ss[tid]*expf(sm[tid]-M) + s2*expf(m2-M);
      sm[tid] = M;
    }
    __syncthreads();
  }
  float M = sm[0];
  float inv = 1.f/ss[0];
  for (int j = tid; j < EV; j += 256) {
    p[j] = expf(p[j] - M) * inv;
  }
}

extern "C" void kernel_launch(void* const* d_in, const int* in_sizes, int n_in,
                              void* d_out, int out_size, void* d_ws, size_t ws_size,
                              hipStream_t stream) {
  (void)in_sizes; (void)n_in; (void)out_size;
  const int*   enc_in  = (const int*)d_in[0];
  const float* femb    = (const float*)d_in[2];
  const float* enc_W   = (const float*)d_in[4];
  const float* enc_U   = (const float*)d_in[5];
  const float* enc_b   = (const float*)d_in[6];
  const float* dec_W   = (const float*)d_in[7];
  const float* dec_U   = (const float*)d_in[8];
  const float* dec_b   = (const float*)d_in[9];
  const float* att_W1  = (const float*)d_in[10];
  const float* att_W2  = (const float*)d_in[11];
  const float* sp1_W   = (const float*)d_in[12];
  const float* sp1_b   = (const float*)d_in[13];
  const float* sp2_W   = (const float*)d_in[14];
  const float* sp2_b   = (const float*)d_in[15];
  const float* ff1_W   = (const float*)d_in[16];
  const float* ff1_b   = (const float*)d_in[17];
  const float* ff2_W   = (const float*)d_in[18];
  const float* ff2_b   = (const float*)d_in[19];
  float* out = (float*)d_out;
  float* ws  = (float*)d_ws;

  float* enc_T  = ws + 0;          // 409600
  float* W_all  = ws + 409600;     // 100*1012 = 101200
  float* h_st   = ws + 510800;     // 6400
  float* dec_o  = ws + 517200;     // 204800
  float* hid    = ws + 722000;     // 204800
  float* vbuf   = ws + 926800;     // 256
  float* c2buf  = ws + 927056;     // 16 (pad)
  float* Q_g    = ws + 927072;     // 4096*1012 = 4145152
  float* xs_all = Q_g;             // aliases Q_g (dead after k_enc, before k_initQ)
  if (ws_size < (size_t)5072224*4) return;   // ~20.3 MB

  k_setup<<<398, 256, 0, stream>>>(att_W1, dec_W, sp1_W, sp2_W, sp2_b, W_all, vbuf, c2buf);
  k_embed<<<4096, 320, 0, stream>>>(enc_in, femb, enc_W, enc_b, xs_all);
  k_enc<<<64, 192, 0, stream>>>(enc_U, enc_b, xs_all, enc_T, h_st);
  k_initQ<<<dim3(8, 32), 256, 0, stream>>>(enc_T, W_all, Q_g);
  k_dec<<<64, 512, 0, stream>>>(Q_g, h_st, dec_U, dec_b, sp1_W, sp1_b,
                                att_W1, att_W2, vbuf, c2buf, dec_o);
  k_ff1<<<2048, 128, 0, stream>>>(dec_o, ff1_W, ff1_b, hid);
  k_logits<<<dim3(157, 16), 256, 0, stream>>>(hid, ff2_W, ff2_b, out);
  k_softmax<<<2048, 256, 0, stream>>>(out);
}

// Round 11
// 1190.121 us; speedup vs baseline: 1.4723x; 1.0948x over previous
//
#include <hip/hip_runtime.h>
#include <math.h>

#define B 64
#define TF 64
#define TE 32
#define E_DIM 40
#define H 100
#define H2 200
#define H3 300
#define SP 256
#define EV 20000
#define ROWS (B*TF)        // 4096
#define NC 1012            // Q cols: Psc200 | PY256 | Qdw300 | Qmid256
#define NHC 956            // W_hT cols: decU300 | sp1Wh256 | attW1top200 | attW2 200

// ---------------- setup: W_all (proj), W_hT (transposed h-weights), v, c2 ----------------
__global__ __launch_bounds__(256) void k_setup(const float* att_W1, const float* att_W2,
        const float* dec_W, const float* dec_U, const float* sp1_W,
        const float* sp2_W, const float* sp2_b,
        float* W_all, float* W_hT, float* v, float* c2) {
  int bid = blockIdx.x;
  if (bid < 396) {
    int idx = bid*256 + threadIdx.x;
    if (idx < 100*NC) {
      int k = idx / NC, c = idx - k*NC;
      float val;
      if (c < 200)      val = att_W1[(100+k)*H2 + c];          // attW1 bottom
      else if (c < 456) val = sp1_W[(200+k)*SP + (c-200)];     // sp1W enc-part
      else if (c < 756) val = dec_W[k*H3 + (c-456)];           // dec_W
      else              val = sp1_W[(100+k)*SP + (c-756)];     // sp1W rd-part
      W_all[idx] = val;
    }
  } else if (bid < 770) {
    int idx = (bid-396)*256 + threadIdx.x;
    if (idx < NHC*100) {
      int c = idx / 100, k = idx - c*100;
      float val;
      if (c < 300)      val = dec_U[k*H3 + c];                 // dec_U
      else if (c < 556) val = sp1_W[k*SP + (c-300)];           // sp1W h-part
      else if (c < 756) val = att_W1[k*H2 + (c-556)];          // attW1 top
      else              val = att_W2[k*H2 + (c-756)];          // attW2
      W_hT[idx] = val;                                         // [c][k] col-major
    }
  } else if (bid == 770) {
    int k = threadIdx.x;
    float s = 0.f;
    for (int j = 0; j < SP; ++j) s += sp2_W[k*SP + j];
    v[k] = s * (1.f/256.f);
  } else {
    if (threadIdx.x == 0) {
      float s = 0.f;
      for (int j = 0; j < SP; ++j) s += sp2_b[j];
      *c2 = s * (1.f/256.f);
    }
  }
}

// ---------------- encoder xs = embed @ enc_W + enc_b[0] ----------------
__global__ __launch_bounds__(320) void k_embed(const int* enc_in, const float* femb,
        const float* enc_W, const float* enc_b, float* xs_all) {
  int row = blockIdx.x;
  int j = threadIdx.x;
  __shared__ __align__(16) float emb[E_DIM];
  int tok = enc_in[row];
  if (j < E_DIM) emb[j] = femb[tok*E_DIM + j];
  __syncthreads();
  if (j < H3) {
    float acc = enc_b[j];
    #pragma unroll
    for (int k = 0; k < E_DIM; ++k) acc += emb[k]*enc_W[k*H3 + j];
    xs_all[row*H3 + j] = acc;
  }
}

// ---------------- encoder GRU recurrence ----------------
__global__ __launch_bounds__(192) void k_enc(const float* __restrict__ enc_U,
        const float* __restrict__ enc_b, const float* __restrict__ xs_all,
        float* __restrict__ enc_T, float* __restrict__ h_state) {
  int b = blockIdx.x, t = threadIdx.x;
  __shared__ __align__(16) float hsh[104];
  __shared__ __align__(16) float hs[304];

  float2 Ur[100];
  float2 bias = {0.f, 0.f};
  if (t < 150) {
    const float* base = enc_U + 2*t;
    #pragma unroll
    for (int k = 0; k < 100; ++k) Ur[k] = *(const float2*)(base + k*H3);
    bias = *(const float2*)(enc_b + H3 + 2*t);
  }
  if (t < H) hsh[t] = 0.f;
  __syncthreads();

  #pragma unroll 1
  for (int step = 0; step < TF; ++step) {
    int row = b*TF + step;
    float xz = 0.f, xr = 0.f, xh = 0.f;
    if (t < H) {
      xz = xs_all[row*H3 + t];
      xr = xs_all[row*H3 + 100 + t];
      xh = xs_all[row*H3 + 200 + t];
    }
    if (t < 150) {
      float a0 = bias.x, a1 = bias.y;
      const float4* h4 = (const float4*)hsh;
      #pragma unroll
      for (int k4 = 0; k4 < 25; ++k4) {
        float4 hv = h4[k4];
        a0 += hv.x*Ur[k4*4+0].x + hv.y*Ur[k4*4+1].x + hv.z*Ur[k4*4+2].x + hv.w*Ur[k4*4+3].x;
        a1 += hv.x*Ur[k4*4+0].y + hv.y*Ur[k4*4+1].y + hv.z*Ur[k4*4+2].y + hv.w*Ur[k4*4+3].y;
      }
      hs[2*t]   = a0;
      hs[2*t+1] = a1;
    }
    __syncthreads();
    if (t < H) {
      float z = 1.f/(1.f+expf(-(xz + hs[t])));
      float r = 1.f/(1.f+expf(-(xr + hs[100+t])));
      float cand = tanhf(xh + r*hs[200+t]);
      float hn = z*hsh[t] + (1.f-z)*cand;
      hsh[t] = hn;
      enc_T[t*ROWS + row] = hn;
    }
    __syncthreads();
  }
  if (t < H) h_state[b*H + t] = hsh[t];
}

// ---------------- Q init: [4096,100] @ [100,1012] tiled GEMM ----------------
#define KC 20
__global__ __launch_bounds__(256) void k_initQ(const float* __restrict__ enc_T,
        const float* __restrict__ W_all, float* __restrict__ Q_g) {
  int bx = blockIdx.x, by = blockIdx.y;
  int tid = threadIdx.x;
  int tx = tid & 15, ty = tid >> 4;
  __shared__ __align__(16) float At[KC*132];
  __shared__ __align__(16) float Wt[KC*132];
  int r0 = by*128;
  int c0 = bx*128;
  float acc[8][8];
  #pragma unroll
  for (int i = 0; i < 8; ++i)
    #pragma unroll
    for (int j = 0; j < 8; ++j) acc[i][j] = 0.f;
  for (int kc = 0; kc < 100; kc += KC) {
    __syncthreads();
    for (int i = tid; i < 128*KC; i += 256) {
      int r = i & 127, kk = i >> 7;
      At[kk*132 + r] = enc_T[(kc+kk)*ROWS + r0 + r];
    }
    for (int i = tid; i < 128*KC; i += 256) {
      int cidx = i & 127, kk = i >> 7;
      int gc = c0 + cidx;
      Wt[kk*132 + cidx] = (gc < NC) ? W_all[(kc+kk)*NC + gc] : 0.f;
    }
    __syncthreads();
    #pragma unroll
    for (int kk = 0; kk < KC; ++kk) {
      const float* Ar = At + kk*132;
      const float* Wr = Wt + kk*132;
      float4 a0 = *(const float4*)(Ar + ty*4);
      float4 a1 = *(const float4*)(Ar + 64 + ty*4);
      float4 w0 = *(const float4*)(Wr + tx*4);
      float4 w1 = *(const float4*)(Wr + 64 + tx*4);
      float av[8] = {a0.x,a0.y,a0.z,a0.w,a1.x,a1.y,a1.z,a1.w};
      float wv[8] = {w0.x,w0.y,w0.z,w0.w,w1.x,w1.y,w1.z,w1.w};
      #pragma unroll
      for (int i = 0; i < 8; ++i)
        #pragma unroll
        for (int j = 0; j < 8; ++j) acc[i][j] += av[i]*wv[j];
    }
  }
  #pragma unroll
  for (int i = 0; i < 8; ++i) {
    int r = r0 + ty*4 + (i < 4 ? i : 60 + i);
    float* orow = Q_g + (size_t)r*NC;
    int ca = c0 + tx*4;
    if (ca < NC) {
      float4 val = {acc[i][0], acc[i][1], acc[i][2], acc[i][3]};
      *(float4*)(orow + ca) = val;
    }
    int cb = c0 + 64 + tx*4;
    if (cb < NC) {
      float4 val = {acc[i][4], acc[i][5], acc[i][6], acc[i][7]};
      *(float4*)(orow + cb) = val;
    }
  }
}

// ---------------- decoder: 64 independent blocks x 1024 threads ----------
// Psc/PY in LDS; ALL 556 Qdw+Qmid cols one-per-thread as 16 NAMED float4
// (cannot spill). h-weights from W_hT (col-major -> 25 float4 loads/col).
// Blends fused into consumers: Psc-blend in P0 scores; PY/reg-blend in P2.
#define Q16(OP) OP(0) OP(1) OP(2) OP(3) OP(4) OP(5) OP(6) OP(7) \
                OP(8) OP(9) OP(10) OP(11) OP(12) OP(13) OP(14) OP(15)
__global__ __launch_bounds__(1024, 1) void k_dec(
    const float* __restrict__ Q_g, const float* __restrict__ h_st,
    const float* __restrict__ W_hT, const float* __restrict__ dec_b,
    const float* __restrict__ sp1_b,
    const float* __restrict__ v_g, const float* __restrict__ c2p,
    float* __restrict__ dec_o) {
  int b = blockIdx.x, tid = threadIdx.x;
  int w = tid >> 6, lane = tid & 63;
  __shared__ float Psc[64*200];             // 51.2 KB
  __shared__ float PYs[64*256];             // 65.5 KB
  __shared__ __align__(16) float Rsh[1016];
  __shared__ __align__(16) float hL[104];
  __shared__ float hWs[200], qs[200], ccs[256], vL[256], spb[256];
  __shared__ __align__(16) float dbs[600];
  __shared__ float xsx[304], hsx[304];
  __shared__ __align__(16) float scor[64];
  __shared__ __align__(16) float alph[64];
  __shared__ __align__(16) float gsh[64];

  // one Q column per thread (556 owners): tid<300 -> Qdw col 456+tid;
  // 300<=tid<556 -> Qmid col 756+(tid-300). Non-owners get a safe dummy col.
  bool qown = tid < 556;
  int mycol = !qown ? 456 : ((tid < 300) ? (456 + tid) : (756 + (tid - 300)));
  const float* Qb = Q_g + (size_t)b*64*NC;

#define DECLQ(i) float4 q##i;
  Q16(DECLQ)

  // ---- prologue: load state ----
#define LOADQ(i) q##i = make_float4(Qb[(4*i+0)*NC + mycol], Qb[(4*i+1)*NC + mycol], \
                                    Qb[(4*i+2)*NC + mycol], Qb[(4*i+3)*NC + mycol]);
  Q16(LOADQ)
  for (int i = tid; i < 12800; i += 1024) {
    int t = i / 200, c = i - t*200;
    Psc[i] = Qb[t*NC + c];
  }
  for (int i = tid; i < 16384; i += 1024) {
    int t = i >> 8, j = i & 255;
    PYs[i] = Qb[t*NC + 200 + j];
  }
  if (tid < 256) { vL[tid] = v_g[tid]; spb[tid] = sp1_b[tid]; }
  if (tid < 104) hL[tid] = (tid < 100) ? h_st[b*100 + tid] : 0.f;
  if (tid < 600) dbs[tid] = dec_b[tid];
  float c2 = *c2p;
  __syncthreads();
  // initial hW/q from h(-1) via W_hT cols 556..955
  if (tid < 400) {
    const float4* wc = (const float4*)(W_hT + (556 + tid)*100);
    const float4* h4 = (const float4*)hL;
    float a = 0.f;
    #pragma unroll
    for (int k4 = 0; k4 < 25; ++k4) {
      float4 wv = wc[k4], hv = h4[k4];
      a += hv.x*wv.x + hv.y*wv.y + hv.z*wv.z + hv.w*wv.w;
    }
    if (tid < 200) hWs[tid] = a; else qs[tid-200] = a;
  }
  __syncthreads();

  #pragma unroll 1
  for (int s = 0; s < TE; ++s) {
    // P0: [s>0: fused Psc blend with g(s-1),R(s-1)] + scores(s)
    if (s > 0) {
      #pragma unroll
      for (int i = 0; i < 4; ++i) {
        int t = w*4 + i;
        float gt = gsh[t], om = 1.f - gt;
        float sp = 0.f;
        for (int c = lane; c < 200; c += 64) {
          float nv = gt*Psc[t*200 + c] + om*Rsh[c];
          Psc[t*200 + c] = nv;
          sp += tanhf(hWs[c] + nv) * qs[c];
        }
        #pragma unroll
        for (int mk = 32; mk >= 1; mk >>= 1) sp += __shfl_xor(sp, mk);
        if (lane == 0) scor[t] = sp;
      }
    } else {
      #pragma unroll
      for (int i = 0; i < 4; ++i) {
        int t = w*4 + i;
        float sp = 0.f;
        for (int c = lane; c < 200; c += 64)
          sp += tanhf(hWs[c] + Psc[t*200 + c]) * qs[c];
        #pragma unroll
        for (int mk = 32; mk >= 1; mk >>= 1) sp += __shfl_xor(sp, mk);
        if (lane == 0) scor[t] = sp;
      }
    }
    __syncthreads();
    // P1: softmax over t (wave 0)
    if (w == 0) {
      float sc = scor[lane];
      float m = sc;
      #pragma unroll
      for (int mk = 32; mk >= 1; mk >>= 1) m = fmaxf(m, __shfl_xor(m, mk));
      float ex = expf(sc - m);
      float ssum = ex;
      #pragma unroll
      for (int mk = 32; mk >= 1; mk >>= 1) ssum += __shfl_xor(ssum, mk);
      alph[lane] = ex / ssum;
    }
    __syncthreads();
    // P2: fused [blend with g(s-1)] + R(s) = alpha(s) @ Q(s)
    {
      float rvp = Rsh[mycol];                  // own slot's previous R (dummy ok)
      if (s > 0) {
#define BLDQ(i) { float g0 = gsh[4*i+0], g1 = gsh[4*i+1], g2 = gsh[4*i+2], g3 = gsh[4*i+3]; \
        q##i.x = g0*q##i.x + (1.f-g0)*rvp;  q##i.y = g1*q##i.y + (1.f-g1)*rvp; \
        q##i.z = g2*q##i.z + (1.f-g2)*rvp;  q##i.w = g3*q##i.w + (1.f-g3)*rvp; }
        Q16(BLDQ)
      }
      float rr = 0.f;
#define REDQ(i) rr += alph[4*i+0]*q##i.x + alph[4*i+1]*q##i.y \
                    + alph[4*i+2]*q##i.z + alph[4*i+3]*q##i.w;
      Q16(REDQ)
      if (qown) Rsh[mycol] = rr;
    }
    if (tid >= 556 && tid < 756) {
      int c = tid - 556;                       // Psc already blended in P0
      float rs = 0.f;
      #pragma unroll 8
      for (int t = 0; t < 64; ++t) rs += alph[t]*Psc[t*200 + c];
      Rsh[c] = rs;
    } else if (tid >= 756 && tid < 1012) {
      int j = tid - 756;
      float rvp = Rsh[200 + j];
      float rp = 0.f;
      if (s > 0) {
        #pragma unroll 8
        for (int t = 0; t < 64; ++t) {
          float g = gsh[t];
          float nv = g*PYs[t*256 + j] + (1.f-g)*rvp;
          PYs[t*256 + j] = nv;
          rp += alph[t]*nv;
        }
      } else {
        #pragma unroll 8
        for (int t = 0; t < 64; ++t) rp += alph[t]*PYs[t*256 + j];
      }
      Rsh[200 + j] = rp;
    }
    __syncthreads();
    // P3: hs = h @ dec_U + b1 (W_hT cols 0..299, 25 float4/col); xs = R_dw + b0
    if (tid < 300) {
      const float4* wc = (const float4*)(W_hT + tid*100);
      const float4* h4 = (const float4*)hL;
      float a = dbs[300 + tid];
      #pragma unroll
      for (int k4 = 0; k4 < 25; ++k4) {
        float4 wv = wc[k4], hv = h4[k4];
        a += hv.x*wv.x + hv.y*wv.y + hv.z*wv.z + hv.w*wv.w;
      }
      hsx[tid] = a;
      xsx[tid] = Rsh[456 + tid] + dbs[tid];
    }
    __syncthreads();
    // P3b: GRU gate update -> h(s)
    if (tid < 100) {
      float xz = xsx[tid], xr = xsx[100+tid], xh = xsx[200+tid];
      float hz = hsx[tid], hr = hsx[100+tid], hh = hsx[200+tid];
      float hv = hL[tid];
      float z = 1.f/(1.f+expf(-(xz+hz)));
      float r = 1.f/(1.f+expf(-(xr+hr)));
      float cand = tanhf(xh + r*hh);
      float hn = z*hv + (1.f-z)*cand;
      hL[tid] = hn;
      dec_o[(b*TE + s)*H + tid] = hn;
    }
    __syncthreads();
    // P4: cc_h | hW | q from h(s) (W_hT cols 300..955, one col/thread)
    if (tid < 656) {
      const float4* wc = (const float4*)(W_hT + (300 + tid)*100);
      const float4* h4 = (const float4*)hL;
      float a = 0.f;
      #pragma unroll
      for (int k4 = 0; k4 < 25; ++k4) {
        float4 wv = wc[k4], hv = h4[k4];
        a += hv.x*wv.x + hv.y*wv.y + hv.z*wv.z + hv.w*wv.w;
      }
      if (tid < 256)      ccs[tid] = a + Rsh[756 + tid] + spb[tid];
      else if (tid < 456) hWs[tid - 256] = a;
      else                qs[tid - 456] = a;
    }
    __syncthreads();
    // P5: gate g_t = sigmoid( sum_j relu(cc_j + PY[t,j]) v_j + c2 )
    #pragma unroll
    for (int i = 0; i < 4; ++i) {
      int t = w*4 + i;
      float gp = 0.f;
      #pragma unroll
      for (int jj = 0; jj < 4; ++jj) {
        int j = lane + jj*64;
        gp += fmaxf(ccs[j] + PYs[t*256 + j], 0.f) * vL[j];
      }
      #pragma unroll
      for (int mk = 32; mk >= 1; mk >>= 1) gp += __shfl_xor(gp, mk);
      if (lane == 0) gsh[t] = 1.f/(1.f+expf(-(gp + c2)));
    }
    __syncthreads();
  }
}

// ---------------- ff1: hid = relu(dec_out @ ff1_W + b) ----------------
__global__ __launch_bounds__(128) void k_ff1(const float* dec_out, const float* ff1_W,
        const float* ff1_b, float* hid) {
  int row = blockIdx.x, j = threadIdx.x;
  __shared__ __align__(16) float a[104];
  if (j < H) a[j] = dec_out[row*H + j];
  __syncthreads();
  if (j < H) {
    float acc = ff1_b[j];
    const float4* a4 = (const float4*)a;
    #pragma unroll
    for (int k4 = 0; k4 < 25; ++k4) {
      float4 av = a4[k4];
      int k = k4*4;
      acc += av.x*ff1_W[(k+0)*H+j] + av.y*ff1_W[(k+1)*H+j] + av.z*ff1_W[(k+2)*H+j] + av.w*ff1_W[(k+3)*H+j];
    }
    hid[row*H + j] = fmaxf(acc, 0.f);
  }
}

// ---------------- logits GEMM: [2048,100] x [100,20000] ----------------
__global__ __launch_bounds__(256) void k_logits(const float* hid, const float* ff2_W,
        const float* ff2_b, float* out) {
  int bx = blockIdx.x, by = blockIdx.y;
  int tid = threadIdx.x;
  int tx = tid & 15, ty = tid >> 4;
  __shared__ __align__(16) float At[KC*132];
  __shared__ __align__(16) float Wt[KC*132];
  int r0 = by*128;
  int c0 = bx*128;
  float acc[8][8];
  #pragma unroll
  for (int i = 0; i < 8; ++i) {
    #pragma unroll
    for (int j = 0; j < 8; ++j) acc[i][j] = 0.f;
  }
  for (int kc = 0; kc < 100; kc += KC) {
    __syncthreads();
    for (int i = tid; i < 128*KC; i += 256) {
      int r = i & 127, kk = i >> 7;
      At[kk*132 + r] = hid[(r0+r)*H + kc + kk];
    }
    for (int i = tid; i < 128*KC; i += 256) {
      int cidx = i & 127, kk = i >> 7;
      int gc = c0 + cidx;
      Wt[kk*132 + cidx] = (gc < EV) ? ff2_W[(size_t)(kc+kk)*EV + gc] : 0.f;
    }
    __syncthreads();
    #pragma unroll
    for (int kk = 0; kk < KC; ++kk) {
      const float* Ar = At + kk*132;
      const float* Wr = Wt + kk*132;
      float4 a0 = *(const float4*)(Ar + ty*4);
      float4 a1 = *(const float4*)(Ar + 64 + ty*4);
      float4 w0 = *(const float4*)(Wr + tx*4);
      float4 w1 = *(const float4*)(Wr + 64 + tx*4);
      float av[8] = {a0.x,a0.y,a0.z,a0.w,a1.x,a1.y,a1.z,a1.w};
      float wv[8] = {w0.x,w0.y,w0.z,w0.w,w1.x,w1.y,w1.z,w1.w};
      #pragma unroll
      for (int i = 0; i < 8; ++i) {
        #pragma unroll
        for (int j = 0; j < 8; ++j) acc[i][j] += av[i]*wv[j];
      }
    }
  }
  #pragma unroll
  for (int i = 0; i < 8; ++i) {
    int r = r0 + ty*4 + (i < 4 ? i : 60 + i);
    float* orow = out + (size_t)r*EV;
    int ca = c0 + tx*4;
    if (ca < EV) {
      float4 bb = *(const float4*)(ff2_b + ca);
      float4 val = {acc[i][0]+bb.x, acc[i][1]+bb.y, acc[i][2]+bb.z, acc[i][3]+bb.w};
      *(float4*)(orow + ca) = val;
    }
    int cb = c0 + 64 + tx*4;
    if (cb < EV) {
      float4 bb = *(const float4*)(ff2_b + cb);
      float4 val = {acc[i][4]+bb.x, acc[i][5]+bb.y, acc[i][6]+bb.z, acc[i][7]+bb.w};
      *(float4*)(orow + cb) = val;
    }
  }
}

// ---------------- in-place row softmax ----------------
__global__ __launch_bounds__(256) void k_softmax(float* out) {
  int row = blockIdx.x, tid = threadIdx.x;
  float* p = out + (size_t)row*EV;
  float m = -1e30f, ssum = 0.f;
  for (int j = tid; j < EV; j += 256) {
    float x = p[j];
    if (x > m) { ssum = ssum*expf(m - x) + 1.f; m = x; }
    else ssum += expf(x - m);
  }
  __shared__ float sm[256], ss[256];
  sm[tid] = m; ss[tid] = ssum;
  __syncthreads();
  for (int st = 128; st >= 1; st >>= 1) {
    if (tid < st) {
      float m2 = sm[tid+st], s2 = ss[tid+st];
      float M = fmaxf(sm[tid], m2);
      ss[tid] = ss[tid]*expf(sm[tid]-M) + s2*expf(m2-M);
      sm[tid] = M;
    }
    __syncthreads();
  }
  float M = sm[0];
  float inv = 1.f/ss[0];
  for (int j = tid; j < EV; j += 256) {
    p[j] = expf(p[j] - M) * inv;
  }
}

extern "C" void kernel_launch(void* const* d_in, const int* in_sizes, int n_in,
                              void* d_out, int out_size, void* d_ws, size_t ws_size,
                              hipStream_t stream) {
  (void)in_sizes; (void)n_in; (void)out_size;
  const int*   enc_in  = (const int*)d_in[0];
  const float* femb    = (const float*)d_in[2];
  const float* enc_W   = (const float*)d_in[4];
  const float* enc_U   = (const float*)d_in[5];
  const float* enc_b   = (const float*)d_in[6];
  const float* dec_W   = (const float*)d_in[7];
  const float* dec_U   = (const float*)d_in[8];
  const float* dec_b   = (const float*)d_in[9];
  const float* att_W1  = (const float*)d_in[10];
  const float* att_W2  = (const float*)d_in[11];
  const float* sp1_W   = (const float*)d_in[12];
  const float* sp1_b   = (const float*)d_in[13];
  const float* sp2_W   = (const float*)d_in[14];
  const float* sp2_b   = (const float*)d_in[15];
  const float* ff1_W   = (const float*)d_in[16];
  const float* ff1_b   = (const float*)d_in[17];
  const float* ff2_W   = (const float*)d_in[18];
  const float* ff2_b   = (const float*)d_in[19];
  float* out = (float*)d_out;
  float* ws  = (float*)d_ws;

  float* enc_T  = ws + 0;          // 409600
  float* W_all  = ws + 409600;     // 100*1012 = 101200
  float* W_hT   = ws + 510800;     // 956*100  = 95600
  float* h_st   = ws + 606400;     // 6400
  float* dec_o  = ws + 612800;     // 204800
  float* hid    = ws + 817600;     // 204800
  float* vbuf   = ws + 1022400;    // 256
  float* c2buf  = ws + 1022656;    // 16 (pad)
  float* Q_g    = ws + 1022672;    // 4096*1012 = 4145152
  float* xs_all = Q_g;             // aliases Q_g (dead after k_enc, before k_initQ)
  if (ws_size < (size_t)5167824*4) return;   // ~20.7 MB

  k_setup<<<772, 256, 0, stream>>>(att_W1, att_W2, dec_W, dec_U, sp1_W,
                                   sp2_W, sp2_b, W_all, W_hT, vbuf, c2buf);
  k_embed<<<4096, 320, 0, stream>>>(enc_in, femb, enc_W, enc_b, xs_all);
  k_enc<<<64, 192, 0, stream>>>(enc_U, enc_b, xs_all, enc_T, h_st);
  k_initQ<<<dim3(8, 32), 256, 0, stream>>>(enc_T, W_all, Q_g);
  k_dec<<<64, 1024, 0, stream>>>(Q_g, h_st, W_hT, dec_b, sp1_b, vbuf, c2buf, dec_o);
  k_ff1<<<2048, 128, 0, stream>>>(dec_o, ff1_W, ff1_b, hid);
  k_logits<<<dim3(157, 16), 256, 0, stream>>>(hid, ff2_W, ff2_b, out);
  k_softmax<<<2048, 256, 0, stream>>>(out);
}